// Round 8
// baseline (979.702 us; speedup 1.0000x reference)
//
#include <hip/hip_runtime.h>

#define TB 8
#define TC 64
#define TT 300
#define TDD 161
#define TH 128
#define TO 64
#define TN (TB * TDD)          // 1288 sequences
#define TWOH 256
#define TILE 16
#define NBLK 81                // ceil(1288/16)
#define NKS 6                  // (C+H)/32
#define ODCH (TO * TDD)        // 10304 channels
#define TOTAL (TB * TO * TT * TDD)      // 24729600
#define AFRAG (NKS * 4 * 16 * 8)        // 3072 ushorts per A-frag buffer
#define TTD (TT * TDD)

typedef __attribute__((ext_vector_type(8))) short bf16x8;
typedef __attribute__((ext_vector_type(4))) float f32x4;

#define MFMA __builtin_amdgcn_mfma_f32_16x16x32_bf16

__device__ __forceinline__ ushort f2bf(float f) {
  union { float f; unsigned u; } v; v.f = f;
  return (ushort)((v.u + 0x7fffu + ((v.u >> 16) & 1u)) >> 16);  // RNE
}
__device__ __forceinline__ unsigned pk2bf(float lo, float hi) {
  unsigned r;
  asm("v_cvt_pk_bf16_f32 %0, %1, %2" : "=v"(r) : "v"(lo), "v"(hi));
  return r;
}

// k-mapping inside a 16x16x32 fragment; identical convention everywhere so any
// permutation error cancels in the contraction (verified R1-R7).
__device__ __forceinline__ int kmap(int e, int q) {
  return ((e < 4) ? 0 : 16) + q * 4 + (e & 3);
}
// Swizzled ushort index of (row, kg) in the A-frag buffer (kg in [0,192)).
__device__ __forceinline__ int aidx_sw(int row, int kg) {
  int ks = kg >> 5, k32 = kg & 31;
  int half = k32 >> 4, qq = (k32 >> 2) & 3, em = k32 & 3;
  int B = (ks * 4 + qq) * 16 + (row ^ qq);
  return B * 8 + half * 4 + em;
}

// V=0: real recurrence (h-history store, no y-path).
// V=1: diag skeleton — ds_reads (sunk) + packs + LDS/global h writes + barrier,
//      no MFMA, no gates. V=2/3 kept for future ablation (not launched).
template<int V>
__global__ __launch_bounds__(512) void gru_kernel(
    const float* __restrict__ x, const int* __restrict__ lengths,
    const float* __restrict__ Wx, const float* __restrict__ Wh,
    const float* __restrict__ bias, ushort* __restrict__ hh,
    float* __restrict__ wsH, float* __restrict__ diag,
    int t0, int t1, int smask)
{
  __shared__ __align__(16) ushort ldsA[2][AFRAG];
  __shared__ int s_b[TILE], s_d[TILE], s_len[TILE], s_ok[TILE];

  const int tid = threadIdx.x;
  const int w = tid >> 6, l = tid & 63, q = l >> 4, r = l & 15;
  const int rxq = r ^ q;
  const int blk = blockIdx.x;

  if (tid < TILE) {
    int n = blk * TILE + tid;
    int ok = (n < TN) ? 1 : 0;
    int b = ok ? (n / TDD) : 0;
    int d = ok ? (n - b * TDD) : 0;
    s_b[tid] = b; s_d[tid] = d; s_ok[tid] = ok;
    s_len[tid] = ok ? lengths[b] : -1;
  }
  __syncthreads();

  // ---- x loader mapping: thread -> (c = tid/8, nn = (tid%8)*2 + {0,1})
  const int xc = tid >> 3;
  const int xn0 = (tid & 7) * 2;
  int xok[2], xbase[2], xa[2];
  #pragma unroll
  for (int j = 0; j < 2; j++) {
    int nn = xn0 + j;
    xok[j] = s_ok[nn];
    xbase[j] = (s_b[nn] * TC + xc) * TTD + s_d[nn];
    xa[j] = aidx_sw(nn, xc);
  }
  // x(t0) into buffer 0; rotation depth 4
  #pragma unroll
  for (int j = 0; j < 2; j++) {
    float v = xok[j] ? x[xbase[j] + t0 * TDD] : 0.0f;
    ldsA[0][xa[j]] = f2bf(v);
  }
  int tp1 = t0 + 1, tp2 = (t0 + 2 < TT) ? t0 + 2 : TT - 1, tp3 = (t0 + 3 < TT) ? t0 + 3 : TT - 1;
  float wx0 = xok[0] ? x[xbase[0] + tp1 * TDD] : 0.0f;
  float wx1 = xok[1] ? x[xbase[1] + tp1 * TDD] : 0.0f;
  float sx0 = xok[0] ? x[xbase[0] + tp2 * TDD] : 0.0f;
  float sx1 = xok[1] ? x[xbase[1] + tp2 * TDD] : 0.0f;
  float tx0 = xok[0] ? x[xbase[0] + tp3 * TDD] : 0.0f;
  float tx1 = xok[1] ? x[xbase[1] + tp3 * TDD] : 0.0f;

  // ---- gate B-fragments from [Wx; Wh]; c-gate pre-scaled by 2 (exact)
  bf16x8 wf[2][NKS];
  const int ucol = w * 16 + r;
  #pragma unroll
  for (int jj = 0; jj < 2; jj++) {
    int col = jj * TH + ucol;
    float sc = jj ? 2.0f : 1.0f;
    #pragma unroll
    for (int ks = 0; ks < NKS; ks++) {
      bf16x8 f;
      #pragma unroll
      for (int e = 0; e < 8; e++) {
        int kg = ks * 32 + kmap(e, q);
        float v = (kg < TC) ? Wx[kg * TWOH + col] : Wh[(kg - TC) * TWOH + col];
        f[e] = (short)f2bf(sc * v);
      }
      wf[jj][ks] = f;
    }
  }
  const float bz = bias[ucol];
  const float bc = 2.0f * bias[TH + ucol];

  int llen[4];
  #pragma unroll
  for (int i = 0; i < 4; i++) llen[i] = s_len[q * 4 + i];

  // h state (+ restore from checkpoint for chunked runs)
  float hreg[4];
  int hwi[4];
  #pragma unroll
  for (int i = 0; i < 4; i++) hwi[i] = aidx_sw(q * 4 + i, TC + ucol);
  if (t0 == 0) {
    #pragma unroll
    for (int i = 0; i < 4; i++) hreg[i] = 0.0f;
    for (int i = tid; i < AFRAG - 1024; i += 512) ldsA[0][1024 + i] = 0;
  } else {
    const float* hp = &wsH[(blk * TH + ucol) * 16 + q * 4];
    #pragma unroll
    for (int i = 0; i < 4; i++) {
      hreg[i] = hp[i];
      ldsA[0][hwi[i]] = f2bf(hreg[i]);
    }
  }
  uint2* hhu = (uint2*)hh;
  __syncthreads();

#define STEP(T_, PAR)                                                          \
  {                                                                            \
    const int t_ = (T_);                                                       \
    int tc = t_ + 4; tc = (tc < TT) ? tc : (TT - 1);                           \
    float nx0 = xok[0] ? x[xbase[0] + tc * TDD] : 0.0f;                        \
    float nx1 = xok[1] ? x[xbase[1] + tc * TDD] : 0.0f;                        \
    const ushort* Ab = ldsA[PAR];                                              \
    bf16x8 af0 = *(const bf16x8*)&Ab[((0 * 4 + q) * 16 + rxq) * 8];            \
    bf16x8 af1 = *(const bf16x8*)&Ab[((1 * 4 + q) * 16 + rxq) * 8];            \
    bf16x8 af2 = *(const bf16x8*)&Ab[((2 * 4 + q) * 16 + rxq) * 8];            \
    bf16x8 af3 = *(const bf16x8*)&Ab[((3 * 4 + q) * 16 + rxq) * 8];            \
    bf16x8 af4 = *(const bf16x8*)&Ab[((4 * 4 + q) * 16 + rxq) * 8];            \
    bf16x8 af5 = *(const bf16x8*)&Ab[((5 * 4 + q) * 16 + rxq) * 8];            \
    if constexpr (V == 1) {                                                    \
      asm volatile("" :: "v"(af0), "v"(af1), "v"(af2), "v"(af3),               \
                         "v"(af4), "v"(af5));                                  \
    }                                                                          \
    f32x4 az, az2, ac, ac2;                                                    \
    if constexpr (V == 0 || V >= 2) {                                          \
      az  = f32x4{bz, bz, bz, bz}; az2 = f32x4{0, 0, 0, 0};                    \
      ac  = f32x4{bc, bc, bc, bc}; ac2 = f32x4{0, 0, 0, 0};                    \
      __builtin_amdgcn_s_setprio(1);                                           \
      az  = MFMA(af0, wf[0][0], az,  0, 0, 0);                                 \
      az2 = MFMA(af1, wf[0][1], az2, 0, 0, 0);                                 \
      ac  = MFMA(af0, wf[1][0], ac,  0, 0, 0);                                 \
      ac2 = MFMA(af1, wf[1][1], ac2, 0, 0, 0);                                 \
      az  = MFMA(af2, wf[0][2], az,  0, 0, 0);                                 \
      az2 = MFMA(af3, wf[0][3], az2, 0, 0, 0);                                 \
      ac  = MFMA(af2, wf[1][2], ac,  0, 0, 0);                                 \
      ac2 = MFMA(af3, wf[1][3], ac2, 0, 0, 0);                                 \
      az  = MFMA(af4, wf[0][4], az,  0, 0, 0);                                 \
      az2 = MFMA(af5, wf[0][5], az2, 0, 0, 0);                                 \
      ac  = MFMA(af4, wf[1][4], ac,  0, 0, 0);                                 \
      ac2 = MFMA(af5, wf[1][5], ac2, 0, 0, 0);                                 \
      __builtin_amdgcn_s_setprio(0);                                           \
    }                                                                          \
    unsigned hp01, hp23;                                                       \
    if constexpr (V == 0 || V == 3) {                                          \
      _Pragma("unroll")                                                        \
      for (int i = 0; i < 4; i++) {                                            \
        float a_ = az[i] + az2[i];                                             \
        float b_ = ac[i] + ac2[i];                                             \
        float zv = __builtin_amdgcn_rcpf(1.0f + __expf(-a_));                  \
        float hc = 1.0f - 2.0f * __builtin_amdgcn_rcpf(1.0f + __expf(b_));     \
        float h  = hc + zv * (hreg[i] - hc);                                   \
        hreg[i] = (t_ < llen[i]) ? h : hreg[i];                                \
      }                                                                        \
      hp01 = pk2bf(hreg[0], hreg[1]);                                          \
      hp23 = pk2bf(hreg[2], hreg[3]);                                          \
    } else if constexpr (V == 2) {                                             \
      asm volatile("" :: "v"(ac), "v"(ac2));                                   \
      hp01 = pk2bf(az[0] + az2[0], az[1] + az2[1]);                            \
      hp23 = pk2bf(az[2] + az2[2], az[3] + az2[3]);                            \
    } else {                                                                   \
      hp01 = pk2bf(hreg[0], hreg[1]);                                          \
      hp23 = pk2bf(hreg[2], hreg[3]);                                          \
    }                                                                          \
    if constexpr (V != 3) {  /* coalesced h-history store, fire-and-forget */  \
      int s_ = (t_ - t0) & smask;                                              \
      uint2 hv; hv.x = hp01; hv.y = hp23;                                      \
      hhu[(((size_t)s_ * NBLK + blk) << 9) + (ucol << 2) + q] = hv;            \
    }                                                                          \
    ushort* Aw = ldsA[(PAR) ^ 1];                                              \
    Aw[hwi[0]] = (ushort)hp01; Aw[hwi[1]] = (ushort)(hp01 >> 16);              \
    Aw[hwi[2]] = (ushort)hp23; Aw[hwi[3]] = (ushort)(hp23 >> 16);              \
    unsigned xp = pk2bf(wx0, wx1);                                             \
    Aw[xa[0]] = (ushort)xp; Aw[xa[1]] = (ushort)(xp >> 16);                    \
    wx0 = sx0; wx1 = sx1; sx0 = tx0; sx1 = tx1; tx0 = nx0; tx1 = nx1;          \
    asm volatile("s_waitcnt lgkmcnt(0)" ::: "memory");                         \
    __builtin_amdgcn_s_barrier();                                              \
    __builtin_amdgcn_sched_barrier(0);                                         \
  }

  for (int t = t0; t < t1; t += 2) {
    STEP(t, 0)
    STEP(t + 1, 1)
  }
#undef STEP

  if constexpr (V == 0) {
    float* hp = &wsH[(blk * TH + ucol) * 16 + q * 4];
    #pragma unroll
    for (int i = 0; i < 4; i++) hp[i] = hreg[i];
  } else {
    diag[blk * 512 + tid] = hreg[0] + hreg[1] + hreg[2] + hreg[3];
  }
}

// ---------------- ypost: y = h @ Wo + bo, store + masked BN stats --------
__global__ __launch_bounds__(256) void ypost_kernel(
    const int* __restrict__ lengths, const float* __restrict__ Wo,
    const float* __restrict__ bo, const ushort* __restrict__ hh,
    float* __restrict__ out, float* __restrict__ wsStats, int t0, int t1)
{
  __shared__ __align__(16) ushort hst[4][2048];   // per-wave h staging
  __shared__ float yts[4][16 * 17 + 4];           // per-wave transpose tile
  __shared__ float sstat[2][1024];                // block stats [sum/sq][o*16+n]
  const int tid = threadIdx.x;
  const int w = tid >> 6, l = tid & 63, q = l >> 4, r = l & 15;
  const int blk = blockIdx.x, g = blockIdx.y;

  const int nT = r;                      // lane's seq slot (transposed roles)
  const int n = blk * 16 + nT;
  const int okT = (n < TN);
  const int bT = okT ? (n / TDD) : 0;
  const int dT = okT ? (n - bT * TDD) : 0;
  const int lenT = okT ? lengths[bT] : -1;

  for (int i = tid; i < 2048; i += 256) ((float*)sstat)[i] = 0.0f;

  // Wo B-frags (all 4 o-tiles per wave) + bias
  bf16x8 wo[4][4];
  float bo4[4];
  #pragma unroll
  for (int jt = 0; jt < 4; jt++) {
    #pragma unroll
    for (int ks = 0; ks < 4; ks++) {
      bf16x8 f;
      #pragma unroll
      for (int e = 0; e < 8; e++)
        f[e] = (short)f2bf(Wo[(ks * 32 + kmap(e, q)) * TO + jt * 16 + r]);
      wo[jt][ks] = f;
    }
    bo4[jt] = bo[jt * 16 + r];
  }
  float ysum[16], ysq[16];
  #pragma unroll
  for (int i = 0; i < 16; i++) { ysum[i] = 0.0f; ysq[i] = 0.0f; }
  __syncthreads();

  const int len = t1 - t0;
  const int half = (len + 1) >> 1;
  const int sbeg = g * half;
  const int send = (len < sbeg + half) ? len : sbeg + half;

  for (int s = sbeg + w; s < send; s += 4) {
    const ushort* hp = hh + (((size_t)s * NBLK + blk) << 11);
    ushort* hl = hst[w];
    #pragma unroll
    for (int e4 = 0; e4 < 4; e4++)
      *(bf16x8*)&hl[l * 32 + e4 * 8] = *(const bf16x8*)&hp[l * 32 + e4 * 8];
    bf16x8 af[4];
    #pragma unroll
    for (int ks = 0; ks < 4; ks++) {
      bf16x8 f;
      #pragma unroll
      for (int e = 0; e < 8; e++)
        f[e] = (short)hl[(ks * 32 + kmap(e, q)) * 16 + r];
      af[ks] = f;
    }
    const int tabs = t0 + s;
    const bool val = (tabs < lenT);
    float* yt = yts[w];
    #pragma unroll
    for (int jt = 0; jt < 4; jt++) {
      f32x4 acc = {bo4[jt], bo4[jt], bo4[jt], bo4[jt]};
      acc = MFMA(af[0], wo[jt][0], acc, 0, 0, 0);
      acc = MFMA(af[1], wo[jt][1], acc, 0, 0, 0);
      acc = MFMA(af[2], wo[jt][2], acc, 0, 0, 0);
      acc = MFMA(af[3], wo[jt][3], acc, 0, 0, 0);
      #pragma unroll
      for (int i = 0; i < 4; i++) yt[r * 17 + q * 4 + i] = acc[i];
      #pragma unroll
      for (int j = 0; j < 4; j++) {
        float v = yt[((l >> 4) + 4 * j) * 17 + nT];
        int oj = jt * 16 + (l >> 4) + 4 * j;
        if (okT) out[((size_t)(bT * TO + oj)) * TTD + tabs * TDD + dT] = v;
        int ci = jt * 4 + j;
        ysum[ci] += val ? v : 0.0f;
        ysq[ci]  += val ? v * v : 0.0f;
      }
    }
  }
  // regs -> block LDS stats
  #pragma unroll
  for (int ci = 0; ci < 16; ci++) {
    int o = (ci >> 2) * 16 + (l >> 4) + 4 * (ci & 3);
    int c = o * 16 + nT;
    atomicAdd(&sstat[0][c], ysum[ci]);
    atomicAdd(&sstat[1][c], ysq[ci]);
  }
  __syncthreads();
  for (int c = tid; c < 1024; c += 256) {
    int o = c >> 4, nn = c & 15;
    int n2 = blk * 16 + nn;
    if (n2 < TN) {
      int b2 = n2 / TDD, d2 = n2 - b2 * TDD;
      atomicAdd(&wsStats[o * TDD + d2], sstat[0][c]);
      atomicAdd(&wsStats[ODCH + o * TDD + d2], sstat[1][c]);
    }
  }
}

// ---------------- BN finalize: per-channel scale/shift ------------------
__global__ __launch_bounds__(256) void finalize_kernel(
    const int* __restrict__ lengths, const float* __restrict__ gamma,
    const float* __restrict__ beta, float* __restrict__ wsStats)
{
  int ch = blockIdx.x * 256 + threadIdx.x;
  if (ch >= ODCH) return;
  int c = 0;
  #pragma unroll
  for (int b = 0; b < TB; b++) c += lengths[b];
  float inv = 1.0f / (float)c;
  float mean = wsStats[ch] * inv;
  float var = wsStats[ODCH + ch] * inv - mean * mean;
  float sc = rsqrtf(var + 1e-5f) * gamma[ch];
  wsStats[2 * ODCH + ch] = sc;
  wsStats[3 * ODCH + ch] = beta[ch] - mean * sc;
}

// ---------------- normalize (float4, scale/shift table) ------------------
__global__ __launch_bounds__(256) void norm_kernel(
    const int* __restrict__ lengths, const float* __restrict__ ss,
    float* __restrict__ out)
{
  int i4 = blockIdx.x * 256 + threadIdx.x;   // TOTAL/4 exact
  int idx = i4 * 4;
  float vv[4];
  *(float4*)vv = ((const float4*)out)[i4];
  int dq = idx / TDD; int d = idx - dq * TDD;
  int tq = dq / TT;   int tt = dq - tq * TT;
  int o = tq & 63;    int b = tq >> 6;
  float res[4];
  #pragma unroll
  for (int k = 0; k < 4; k++) {
    int ch = o * TDD + d;
    float r_ = 0.0f;
    if (tt < lengths[b])
      r_ = vv[k] * ss[ch] + ss[ODCH + ch];
    res[k] = r_;
    d++;
    if (d == TDD) { d = 0; tt++; if (tt == TT) { tt = 0; o++; if (o == 64) { o = 0; b++; } } }
  }
  ((float4*)out)[i4] = *(float4*)res;
}

extern "C" void kernel_launch(void* const* d_in, const int* in_sizes, int n_in,
                              void* d_out, int out_size, void* d_ws, size_t ws_size,
                              hipStream_t stream)
{
  const float* x       = (const float*)d_in[0];
  const int*   lengths = (const int*)d_in[1];
  const float* Wx      = (const float*)d_in[2];
  const float* Wh      = (const float*)d_in[3];
  const float* bias    = (const float*)d_in[4];
  const float* Wo      = (const float*)d_in[5];
  const float* bo      = (const float*)d_in[6];
  const float* gamma   = (const float*)d_in[7];
  const float* beta    = (const float*)d_in[8];
  float* out = (float*)d_out;

  float* ws = (float*)d_ws;
  float* wsStats = ws;                              // 4*ODCH
  float* wsH = ws + 4 * ODCH;                       // NBLK*128*16
  float* diag = wsH + NBLK * TH * 16;               // NBLK*512
  ushort* hh = (ushort*)(diag + NBLK * 512);        // h history, bf16
  const size_t fixedB = (size_t)(4 * ODCH + NBLK * TH * 16 + NBLK * 512) * 4;
  const size_t perT = (size_t)NBLK * 2048 * 2;      // 331776 B per timestep

  int tch = TT;
  size_t avail = ws_size > fixedB ? ws_size - fixedB : 0;
  size_t maxT = avail / perT;
  if (maxT < (size_t)TT) {
    tch = ((int)maxT) & ~1;
    if (tch < 2) tch = 2;
  }

  hipMemsetAsync(wsStats, 0, 2 * ODCH * sizeof(float), stream);
  for (int T0 = 0; T0 < TT; T0 += tch) {
    int T1 = T0 + tch; if (T1 > TT) T1 = TT;
    hipLaunchKernelGGL((gru_kernel<0>), dim3(NBLK), dim3(512), 0, stream,
                       x, lengths, Wx, Wh, bias, hh, wsH, diag,
                       T0, T1, 0x3fffffff);
    hipLaunchKernelGGL(ypost_kernel, dim3(NBLK, 2), dim3(256), 0, stream,
                       lengths, Wo, bo, hh, out, wsStats, T0, T1);
  }
  // diag: skeleton loop (no MFMA/gates) at 1400 steps -> lands in top-5
  {
    int smaskd = (tch >= 8) ? 7 : 1;
    hipLaunchKernelGGL((gru_kernel<1>), dim3(NBLK), dim3(512), 0, stream,
                       x, lengths, Wx, Wh, bias, hh, wsH, diag,
                       0, 1400, smaskd);
  }
  hipLaunchKernelGGL(finalize_kernel, dim3((ODCH + 255) / 256), dim3(256), 0, stream,
                     lengths, gamma, beta, wsStats);
  hipLaunchKernelGGL(norm_kernel, dim3(TOTAL / 4 / 256), dim3(256), 0, stream,
                     lengths, wsStats + 2 * ODCH, out);
}

// Round 10
// 414.211 us; speedup vs baseline: 2.3652x; 2.3652x over previous
//
#include <hip/hip_runtime.h>

#define TB 8
#define TC 64
#define TT 300
#define TDD 161
#define TH 128
#define TO 64
#define TN (TB * TDD)          // 1288 sequences
#define TWOH 256
#define TILE 16
#define NBLK 81                // ceil(1288/16)
#define NKS 6                  // (C+H)/32
#define ODCH (TO * TDD)        // 10304 channels
#define TOTAL (TB * TO * TT * TDD)      // 24729600
#define AFRAG (NKS * 4 * 16 * 8)        // 3072 ushorts per A-frag buffer
#define TTD (TT * TDD)

typedef __attribute__((ext_vector_type(8))) short bf16x8;
typedef __attribute__((ext_vector_type(4))) float f32x4;

#define MFMA __builtin_amdgcn_mfma_f32_16x16x32_bf16

__device__ __forceinline__ ushort f2bf(float f) {
  union { float f; unsigned u; } v; v.f = f;
  return (ushort)((v.u + 0x7fffu + ((v.u >> 16) & 1u)) >> 16);  // RNE
}
__device__ __forceinline__ unsigned pk2bf(float lo, float hi) {
  unsigned r;
  asm("v_cvt_pk_bf16_f32 %0, %1, %2" : "=v"(r) : "v"(lo), "v"(hi));
  return r;
}

// k-mapping inside a 16x16x32 fragment; identical convention everywhere so any
// permutation error cancels in the contraction (verified R1-R8).
__device__ __forceinline__ int kmap(int e, int q) {
  return ((e < 4) ? 0 : 16) + q * 4 + (e & 3);
}

// 4-wave recurrence. Wave w owns units [w*32, w*32+32); MFMA col c of tile j
// (j=0,1) is PHYSICAL unit w*32 + 2c + j  ->  lane (q,r) owns units U=w*32+2r
// and U+1 for rows q*4+i. This makes every LDS write contiguous/packable.
__global__ __launch_bounds__(256) void gru_kernel(
    const float* __restrict__ x, const int* __restrict__ lengths,
    const float* __restrict__ Wx, const float* __restrict__ Wh,
    const float* __restrict__ bias, ushort* __restrict__ hh,
    float* __restrict__ wsH, int t0, int t1)
{
  __shared__ __align__(16) ushort ldsA[2][AFRAG];
  __shared__ int s_b[TILE], s_d[TILE], s_len[TILE], s_ok[TILE];

  const int tid = threadIdx.x;
  const int w = tid >> 6, l = tid & 63, q = l >> 4, r = l & 15;
  const int rxq = r ^ q;
  const int blk = blockIdx.x;

  if (tid < TILE) {
    int n = blk * TILE + tid;
    int ok = (n < TN) ? 1 : 0;
    int b = ok ? (n / TDD) : 0;
    int d = ok ? (n - b * TDD) : 0;
    s_b[tid] = b; s_d[tid] = d; s_ok[tid] = ok;
    s_len[tid] = ok ? lengths[b] : -1;
  }
  __syncthreads();

  // ---- x loader: thread -> (nn = tid>>4, c-quad cq = tid&15); 4 consecutive
  // c for one n = 4 consecutive frag ushorts = one b64 LDS write.
  const int xnn = tid >> 4, xcq = tid & 15;
  const int xok = s_ok[xnn];
  const long xbase = (long)(s_b[xnn] * TC + xcq * 4) * TTD + s_d[xnn];
  const int xks = xcq >> 3, xqq = xcq & 3, xhalf = (xcq >> 2) & 1;
  const int xpos = ((xks * 4 + xqq) * 16 + (xnn ^ xqq)) * 8 + xhalf * 4;

#define XLD(T_, D_)                                                            \
  { int tt_ = (T_); tt_ = (tt_ < TT) ? tt_ : (TT - 1);                         \
    _Pragma("unroll")                                                          \
    for (int e = 0; e < 4; e++)                                                \
      D_[e] = xok ? x[xbase + (long)e * TTD + tt_ * TDD] : 0.0f; }

  {  // stage x(t0) into buffer 0
    float cx[4]; XLD(t0, cx)
    uint2 pv; pv.x = pk2bf(cx[0], cx[1]); pv.y = pk2bf(cx[2], cx[3]);
    *(uint2*)&ldsA[0][xpos] = pv;
  }
  float wx[4], sx[4], tx[4], nx[4];
  XLD(t0 + 1, wx) XLD(t0 + 2, sx) XLD(t0 + 3, tx)

  // ---- gate B-frags (registers, once); c-gate pre-scaled by 2 (exact pow2)
  const int U = w * 32 + 2 * r;
  bf16x8 wfz[2][NKS], wfc[2][NKS];
  #pragma unroll
  for (int j = 0; j < 2; j++) {
    #pragma unroll
    for (int ks = 0; ks < NKS; ks++) {
      bf16x8 fz, fc;
      #pragma unroll
      for (int e = 0; e < 8; e++) {
        int kg = ks * 32 + kmap(e, q);
        const float* Wrow = (kg < TC) ? &Wx[kg * TWOH] : &Wh[(kg - TC) * TWOH];
        fz[e] = (short)f2bf(Wrow[U + j]);
        fc[e] = (short)f2bf(2.0f * Wrow[TH + U + j]);
      }
      wfz[j][ks] = fz; wfc[j][ks] = fc;
    }
  }
  const float bz0 = bias[U], bz1 = bias[U + 1];
  const float bc0 = 2.0f * bias[TH + U], bc1 = 2.0f * bias[TH + U + 1];

  int llen[4];
  #pragma unroll
  for (int i = 0; i < 4; i++) llen[i] = s_len[q * 4 + i];

  // h-write positions: row i of unit-pair (U,U+1) -> one aligned u32
  const int hqq = (r >> 1) & 3, hhalf = r >> 3, hem0 = (2 * r) & 3;
  int hwp[4];
  #pragma unroll
  for (int i = 0; i < 4; i++)
    hwp[i] = (((2 + w) * 4 + hqq) * 16 + ((q * 4 + i) ^ hqq)) * 8 + hhalf * 4 + hem0;

  float hreg[2][4];
  if (t0 == 0) {
    #pragma unroll
    for (int j = 0; j < 2; j++)
      #pragma unroll
      for (int i = 0; i < 4; i++) hreg[j][i] = 0.0f;
    for (int i = tid; i < 2048; i += 256) ldsA[0][1024 + i] = 0;
  } else {
    #pragma unroll
    for (int j = 0; j < 2; j++)
      #pragma unroll
      for (int i = 0; i < 4; i++)
        hreg[j][i] = wsH[(blk * TH + U + j) * 16 + q * 4 + i];
    #pragma unroll
    for (int i = 0; i < 4; i++)
      *(unsigned*)&ldsA[0][hwp[i]] = pk2bf(hreg[0][i], hreg[1][i]);
  }
  uint4* hhu4 = (uint4*)hh;
  const int hlane = q * 64 + w * 16 + r;   // uint4 idx within 256-uint4 slot
  __syncthreads();

#define STEP(T_, PAR)                                                          \
  {                                                                            \
    const int t_ = (T_);                                                       \
    XLD(t_ + 4, nx)                                                            \
    const ushort* Ab = ldsA[PAR];                                              \
    bf16x8 af0 = *(const bf16x8*)&Ab[((0 * 4 + q) * 16 + rxq) * 8];            \
    bf16x8 af1 = *(const bf16x8*)&Ab[((1 * 4 + q) * 16 + rxq) * 8];            \
    bf16x8 af2 = *(const bf16x8*)&Ab[((2 * 4 + q) * 16 + rxq) * 8];            \
    bf16x8 af3 = *(const bf16x8*)&Ab[((3 * 4 + q) * 16 + rxq) * 8];            \
    bf16x8 af4 = *(const bf16x8*)&Ab[((4 * 4 + q) * 16 + rxq) * 8];            \
    bf16x8 af5 = *(const bf16x8*)&Ab[((5 * 4 + q) * 16 + rxq) * 8];            \
    f32x4 az0 = {bz0, bz0, bz0, bz0}, az1 = {bz1, bz1, bz1, bz1};              \
    f32x4 ac0 = {bc0, bc0, bc0, bc0}, ac1 = {bc1, bc1, bc1, bc1};              \
    __builtin_amdgcn_s_setprio(1);                                             \
    az0 = MFMA(af0, wfz[0][0], az0, 0, 0, 0);                                  \
    az1 = MFMA(af0, wfz[1][0], az1, 0, 0, 0);                                  \
    ac0 = MFMA(af0, wfc[0][0], ac0, 0, 0, 0);                                  \
    ac1 = MFMA(af0, wfc[1][0], ac1, 0, 0, 0);                                  \
    az0 = MFMA(af1, wfz[0][1], az0, 0, 0, 0);                                  \
    az1 = MFMA(af1, wfz[1][1], az1, 0, 0, 0);                                  \
    ac0 = MFMA(af1, wfc[0][1], ac0, 0, 0, 0);                                  \
    ac1 = MFMA(af1, wfc[1][1], ac1, 0, 0, 0);                                  \
    az0 = MFMA(af2, wfz[0][2], az0, 0, 0, 0);                                  \
    az1 = MFMA(af2, wfz[1][2], az1, 0, 0, 0);                                  \
    ac0 = MFMA(af2, wfc[0][2], ac0, 0, 0, 0);                                  \
    ac1 = MFMA(af2, wfc[1][2], ac1, 0, 0, 0);                                  \
    az0 = MFMA(af3, wfz[0][3], az0, 0, 0, 0);                                  \
    az1 = MFMA(af3, wfz[1][3], az1, 0, 0, 0);                                  \
    ac0 = MFMA(af3, wfc[0][3], ac0, 0, 0, 0);                                  \
    ac1 = MFMA(af3, wfc[1][3], ac1, 0, 0, 0);                                  \
    az0 = MFMA(af4, wfz[0][4], az0, 0, 0, 0);                                  \
    az1 = MFMA(af4, wfz[1][4], az1, 0, 0, 0);                                  \
    ac0 = MFMA(af4, wfc[0][4], ac0, 0, 0, 0);                                  \
    ac1 = MFMA(af4, wfc[1][4], ac1, 0, 0, 0);                                  \
    az0 = MFMA(af5, wfz[0][5], az0, 0, 0, 0);                                  \
    az1 = MFMA(af5, wfz[1][5], az1, 0, 0, 0);                                  \
    ac0 = MFMA(af5, wfc[0][5], ac0, 0, 0, 0);                                  \
    ac1 = MFMA(af5, wfc[1][5], ac1, 0, 0, 0);                                  \
    __builtin_amdgcn_s_setprio(0);                                             \
    _Pragma("unroll")                                                          \
    for (int i = 0; i < 4; i++) {                                              \
      float zv = __builtin_amdgcn_rcpf(1.0f + __expf(-az0[i]));                \
      float hc = 1.0f - 2.0f * __builtin_amdgcn_rcpf(1.0f + __expf(ac0[i]));   \
      float h  = hc + zv * (hreg[0][i] - hc);                                  \
      hreg[0][i] = (t_ < llen[i]) ? h : hreg[0][i];                            \
      zv = __builtin_amdgcn_rcpf(1.0f + __expf(-az1[i]));                      \
      hc = 1.0f - 2.0f * __builtin_amdgcn_rcpf(1.0f + __expf(ac1[i]));         \
      h  = hc + zv * (hreg[1][i] - hc);                                        \
      hreg[1][i] = (t_ < llen[i]) ? h : hreg[1][i];                            \
    }                                                                          \
    {  /* coalesced h-history store (fire & forget) */                         \
      uint4 hv;                                                                \
      hv.x = pk2bf(hreg[0][0], hreg[0][1]);                                    \
      hv.y = pk2bf(hreg[0][2], hreg[0][3]);                                    \
      hv.z = pk2bf(hreg[1][0], hreg[1][1]);                                    \
      hv.w = pk2bf(hreg[1][2], hreg[1][3]);                                    \
      hhu4[((size_t)(t_ - t0) * NBLK + blk) * 256 + hlane] = hv;               \
    }                                                                          \
    ushort* Aw = ldsA[(PAR) ^ 1];                                              \
    *(unsigned*)&Aw[hwp[0]] = pk2bf(hreg[0][0], hreg[1][0]);                   \
    *(unsigned*)&Aw[hwp[1]] = pk2bf(hreg[0][1], hreg[1][1]);                   \
    *(unsigned*)&Aw[hwp[2]] = pk2bf(hreg[0][2], hreg[1][2]);                   \
    *(unsigned*)&Aw[hwp[3]] = pk2bf(hreg[0][3], hreg[1][3]);                   \
    {  /* stage x(t_+1) */                                                     \
      uint2 pv; pv.x = pk2bf(wx[0], wx[1]); pv.y = pk2bf(wx[2], wx[3]);        \
      *(uint2*)&Aw[xpos] = pv;                                                 \
    }                                                                          \
    _Pragma("unroll")                                                          \
    for (int e = 0; e < 4; e++) { wx[e] = sx[e]; sx[e] = tx[e]; tx[e] = nx[e]; } \
    asm volatile("s_waitcnt lgkmcnt(0)" ::: "memory");                         \
    __builtin_amdgcn_s_barrier();                                              \
    __builtin_amdgcn_sched_barrier(0);                                         \
  }

  for (int t = t0; t < t1; t += 2) {
    STEP(t, 0)
    STEP(t + 1, 1)
  }
#undef STEP
#undef XLD

  // checkpoint h for next chunk
  #pragma unroll
  for (int j = 0; j < 2; j++)
    #pragma unroll
    for (int i = 0; i < 4; i++)
      wsH[(blk * TH + U + j) * 16 + q * 4 + i] = hreg[j][i];
}

// ---------------- ypost: y = h @ Wo + bo, store + masked BN stats --------
// hh layout: slot (s,blk) = 2048 ushorts, element (row, u) at
// ((row>>2)*128 + u)*4 + (row&3).
__global__ __launch_bounds__(256) void ypost_kernel(
    const int* __restrict__ lengths, const float* __restrict__ Wo,
    const float* __restrict__ bo, const ushort* __restrict__ hh,
    float* __restrict__ out, float* __restrict__ wsStats, int t0, int t1)
{
  __shared__ __align__(16) ushort hst[4][2048];   // per-wave h staging
  __shared__ float yts[4][16 * 17 + 4];           // per-wave transpose tile
  __shared__ float sstat[2][1024];                // block stats [sum/sq][o*16+n]
  const int tid = threadIdx.x;
  const int w = tid >> 6, l = tid & 63, q = l >> 4, r = l & 15;
  const int blk = blockIdx.x, g = blockIdx.y;

  const int nT = r;
  const int n = blk * 16 + nT;
  const int okT = (n < TN);
  const int bT = okT ? (n / TDD) : 0;
  const int dT = okT ? (n - bT * TDD) : 0;
  const int lenT = okT ? lengths[bT] : -1;

  for (int i = tid; i < 2048; i += 256) ((float*)sstat)[i] = 0.0f;

  bf16x8 wo[4][4];
  float bo4[4];
  #pragma unroll
  for (int jt = 0; jt < 4; jt++) {
    #pragma unroll
    for (int ks = 0; ks < 4; ks++) {
      bf16x8 f;
      #pragma unroll
      for (int e = 0; e < 8; e++)
        f[e] = (short)f2bf(Wo[(ks * 32 + kmap(e, q)) * TO + jt * 16 + r]);
      wo[jt][ks] = f;
    }
    bo4[jt] = bo[jt * 16 + r];
  }
  float ysum[16], ysq[16];
  #pragma unroll
  for (int i = 0; i < 16; i++) { ysum[i] = 0.0f; ysq[i] = 0.0f; }
  __syncthreads();

  const int len = t1 - t0;
  const int half = (len + 1) >> 1;
  const int sbeg = g * half;
  const int send = (len < sbeg + half) ? len : sbeg + half;

  for (int s = sbeg + w; s < send; s += 4) {
    const ushort* hp = hh + (((size_t)s * NBLK + blk) << 11);
    ushort* hl = hst[w];
    #pragma unroll
    for (int e4 = 0; e4 < 4; e4++)
      *(bf16x8*)&hl[l * 32 + e4 * 8] = *(const bf16x8*)&hp[l * 32 + e4 * 8];
    bf16x8 af[4];
    #pragma unroll
    for (int ks = 0; ks < 4; ks++) {
      bf16x8 f;
      #pragma unroll
      for (int e = 0; e < 8; e++) {
        int u = ks * 32 + kmap(e, q);
        f[e] = (short)hl[(((r >> 2) * 128 + u) << 2) + (r & 3)];
      }
      af[ks] = f;
    }
    const int tabs = t0 + s;
    const bool val = (tabs < lenT);
    float* yt = yts[w];
    #pragma unroll
    for (int jt = 0; jt < 4; jt++) {
      f32x4 acc = {bo4[jt], bo4[jt], bo4[jt], bo4[jt]};
      acc = MFMA(af[0], wo[jt][0], acc, 0, 0, 0);
      acc = MFMA(af[1], wo[jt][1], acc, 0, 0, 0);
      acc = MFMA(af[2], wo[jt][2], acc, 0, 0, 0);
      acc = MFMA(af[3], wo[jt][3], acc, 0, 0, 0);
      #pragma unroll
      for (int i = 0; i < 4; i++) yt[r * 17 + q * 4 + i] = acc[i];
      #pragma unroll
      for (int j = 0; j < 4; j++) {
        float v = yt[((l >> 4) + 4 * j) * 17 + nT];
        int oj = jt * 16 + (l >> 4) + 4 * j;
        if (okT) out[((size_t)(bT * TO + oj)) * TTD + tabs * TDD + dT] = v;
        int ci = jt * 4 + j;
        ysum[ci] += val ? v : 0.0f;
        ysq[ci]  += val ? v * v : 0.0f;
      }
    }
  }
  #pragma unroll
  for (int ci = 0; ci < 16; ci++) {
    int o = (ci >> 2) * 16 + (l >> 4) + 4 * (ci & 3);
    int c = o * 16 + nT;
    atomicAdd(&sstat[0][c], ysum[ci]);
    atomicAdd(&sstat[1][c], ysq[ci]);
  }
  __syncthreads();
  for (int c = tid; c < 1024; c += 256) {
    int o = c >> 4, nn = c & 15;
    int n2 = blk * 16 + nn;
    if (n2 < TN) {
      int b2 = n2 / TDD, d2 = n2 - b2 * TDD;
      atomicAdd(&wsStats[o * TDD + d2], sstat[0][c]);
      atomicAdd(&wsStats[ODCH + o * TDD + d2], sstat[1][c]);
    }
  }
}

// ---------------- BN finalize: per-channel scale/shift ------------------
__global__ __launch_bounds__(256) void finalize_kernel(
    const int* __restrict__ lengths, const float* __restrict__ gamma,
    const float* __restrict__ beta, float* __restrict__ wsStats)
{
  int ch = blockIdx.x * 256 + threadIdx.x;
  if (ch >= ODCH) return;
  int c = 0;
  #pragma unroll
  for (int b = 0; b < TB; b++) c += lengths[b];
  float inv = 1.0f / (float)c;
  float mean = wsStats[ch] * inv;
  float var = wsStats[ODCH + ch] * inv - mean * mean;
  float sc = rsqrtf(var + 1e-5f) * gamma[ch];
  wsStats[2 * ODCH + ch] = sc;
  wsStats[3 * ODCH + ch] = beta[ch] - mean * sc;
}

// ---------------- normalize (float4, scale/shift table) ------------------
__global__ __launch_bounds__(256) void norm_kernel(
    const int* __restrict__ lengths, const float* __restrict__ ss,
    float* __restrict__ out)
{
  int i4 = blockIdx.x * 256 + threadIdx.x;   // TOTAL/4 exact
  int idx = i4 * 4;
  float vv[4];
  *(float4*)vv = ((const float4*)out)[i4];
  int dq = idx / TDD; int d = idx - dq * TDD;
  int tq = dq / TT;   int tt = dq - tq * TT;
  int o = tq & 63;    int b = tq >> 6;
  float res[4];
  #pragma unroll
  for (int k = 0; k < 4; k++) {
    int ch = o * TDD + d;
    float r_ = 0.0f;
    if (tt < lengths[b])
      r_ = vv[k] * ss[ch] + ss[ODCH + ch];
    res[k] = r_;
    d++;
    if (d == TDD) { d = 0; tt++; if (tt == TT) { tt = 0; o++; if (o == 64) { o = 0; b++; } } }
  }
  ((float4*)out)[i4] = *(float4*)res;
}

extern "C" void kernel_launch(void* const* d_in, const int* in_sizes, int n_in,
                              void* d_out, int out_size, void* d_ws, size_t ws_size,
                              hipStream_t stream)
{
  const float* x       = (const float*)d_in[0];
  const int*   lengths = (const int*)d_in[1];
  const float* Wx      = (const float*)d_in[2];
  const float* Wh      = (const float*)d_in[3];
  const float* bias    = (const float*)d_in[4];
  const float* Wo      = (const float*)d_in[5];
  const float* bo      = (const float*)d_in[6];
  const float* gamma   = (const float*)d_in[7];
  const float* beta    = (const float*)d_in[8];
  float* out = (float*)d_out;

  float* ws = (float*)d_ws;
  float* wsStats = ws;                              // 4*ODCH
  float* wsH = ws + 4 * ODCH;                       // NBLK*128*16
  ushort* hh = (ushort*)(wsH + NBLK * TH * 16);     // h history, bf16
  const size_t fixedB = (size_t)(4 * ODCH + NBLK * TH * 16) * 4;
  const size_t perT = (size_t)NBLK * 2048 * 2;      // 331776 B per timestep

  int tch = TT;
  size_t avail = ws_size > fixedB ? ws_size - fixedB : 0;
  size_t maxT = avail / perT;
  if (maxT < (size_t)TT) {
    tch = ((int)maxT) & ~1;
    if (tch < 2) tch = 2;
  }

  hipMemsetAsync(wsStats, 0, 2 * ODCH * sizeof(float), stream);
  for (int T0 = 0; T0 < TT; T0 += tch) {
    int T1 = T0 + tch; if (T1 > TT) T1 = TT;
    hipLaunchKernelGGL(gru_kernel, dim3(NBLK), dim3(256), 0, stream,
                       x, lengths, Wx, Wh, bias, hh, wsH, T0, T1);
    hipLaunchKernelGGL(ypost_kernel, dim3(NBLK, 2), dim3(256), 0, stream,
                       lengths, Wo, bo, hh, out, wsStats, T0, T1);
  }
  hipLaunchKernelGGL(finalize_kernel, dim3((ODCH + 255) / 256), dim3(256), 0, stream,
                     lengths, gamma, beta, wsStats);
  hipLaunchKernelGGL(norm_kernel, dim3(TOTAL / 4 / 256), dim3(256), 0, stream,
                     lengths, wsStats + 2 * ODCH, out);
}

// Round 13
// 375.761 us; speedup vs baseline: 2.6072x; 1.1023x over previous
//
#include <hip/hip_runtime.h>

#define TB 8
#define TC 64
#define TT 300
#define TDD 161
#define TH 128
#define TO 64
#define TN (TB * TDD)          // 1288 sequences
#define TWOH 256
#define TILE 16
#define NBLK 81                // ceil(1288/16)
#define NKS 6                  // (C+H)/32
#define ODCH (TO * TDD)        // 10304 channels
#define TOTAL (TB * TO * TT * TDD)      // 24729600
#define AFRAG (NKS * 4 * 16 * 8)        // 3072 ushorts per A-frag buffer
#define TTD (TT * TDD)

typedef __attribute__((ext_vector_type(8))) short bf16x8;
typedef __attribute__((ext_vector_type(4))) float f32x4;

#define MFMA __builtin_amdgcn_mfma_f32_16x16x32_bf16

__device__ __forceinline__ ushort f2bf(float f) {
  union { float f; unsigned u; } v; v.f = f;
  return (ushort)((v.u + 0x7fffu + ((v.u >> 16) & 1u)) >> 16);  // RNE
}
__device__ __forceinline__ unsigned pk2bf(float lo, float hi) {
  unsigned r;
  asm("v_cvt_pk_bf16_f32 %0, %1, %2" : "=v"(r) : "v"(lo), "v"(hi));
  return r;
}

// k-mapping inside a 16x16x32 fragment; identical convention everywhere so any
// permutation error cancels in the contraction (verified R1-R10).
__device__ __forceinline__ int kmap(int e, int q) {
  return ((e < 4) ? 0 : 16) + q * 4 + (e & 3);
}

// 4-wave recurrence. Wave w owns units [w*32,w*32+32); MFMA col c of tile j
// is PHYSICAL unit w*32+2c+j (lane (q,r) owns units U=w*32+2r, U+1).
// x loader: lane -> (slot nn = tid&15, channel-quad cq = tid>>4): consecutive
// lanes cover consecutive d -> HW segment-merging coalesces the gather
// (~90 segments/step vs 1024 with the old mapping).
// x prefetch: 4 distinct register sets (xA..xD), consumed 4 substeps after
// issue with NO copies -> compiler's vmcnt wait lands 4 barriers downstream;
// loads stay in flight across the lgkm-only barriers (T3/T4).
__global__ __launch_bounds__(256) void gru_kernel(
    const float* __restrict__ x, const int* __restrict__ lengths,
    const float* __restrict__ Wx, const float* __restrict__ Wh,
    const float* __restrict__ bias, ushort* __restrict__ hh,
    float* __restrict__ wsH, int t0, int t1)
{
  __shared__ __align__(16) ushort ldsA[2][AFRAG];
  __shared__ int s_b[TILE], s_d[TILE], s_len[TILE], s_ok[TILE];

  const int tid = threadIdx.x;
  const int w = tid >> 6, l = tid & 63, q = l >> 4, r = l & 15;
  const int rxq = r ^ q;
  const int blk = blockIdx.x;

  if (tid < TILE) {
    int n = blk * TILE + tid;
    int ok = (n < TN) ? 1 : 0;
    int b = ok ? (n / TDD) : 0;
    int d = ok ? (n - b * TDD) : 0;
    s_b[tid] = b; s_d[tid] = d; s_ok[tid] = ok;
    s_len[tid] = ok ? lengths[b] : -1;
  }
  __syncthreads();

  // ---- x loader: slot nn = tid&15 (d-adjacent lanes), cq = tid>>4
  const int xnn = tid & 15, xcq = tid >> 4;
  const int xok = s_ok[xnn];
  const long xbase = (long)(s_b[xnn] * TC + xcq * 4) * TTD + s_d[xnn];
  const int xpos = (((xcq >> 3) * 4 + (xcq & 3)) * 16 + (xnn ^ (xcq & 3))) * 8
                   + ((xcq >> 2) & 1) * 4;

#define XLD(T_, D_)                                                            \
  { int tt_ = (T_); tt_ = (tt_ < TT) ? tt_ : (TT - 1);                         \
    _Pragma("unroll")                                                          \
    for (int e = 0; e < 4; e++)                                                \
      D_[e] = xok ? x[xbase + (long)e * TTD + tt_ * TDD] : 0.0f; }

  {  // stage x(t0) into buffer 0
    float cx[4]; XLD(t0, cx)
    uint2 pv; pv.x = pk2bf(cx[0], cx[1]); pv.y = pk2bf(cx[2], cx[3]);
    *(uint2*)&ldsA[0][xpos] = pv;
  }
  float xA[4], xB[4], xC[4], xD[4];
  XLD(t0 + 1, xA) XLD(t0 + 2, xB) XLD(t0 + 3, xC) XLD(t0 + 4, xD)

  // ---- gate B-frags (registers, once); c-gate pre-scaled by 2 (exact pow2)
  const int U = w * 32 + 2 * r;
  bf16x8 wfz[2][NKS], wfc[2][NKS];
  #pragma unroll
  for (int j = 0; j < 2; j++) {
    #pragma unroll
    for (int ks = 0; ks < NKS; ks++) {
      bf16x8 fz, fc;
      #pragma unroll
      for (int e = 0; e < 8; e++) {
        int kg = ks * 32 + kmap(e, q);
        const float* Wrow = (kg < TC) ? &Wx[kg * TWOH] : &Wh[(kg - TC) * TWOH];
        fz[e] = (short)f2bf(Wrow[U + j]);
        fc[e] = (short)f2bf(2.0f * Wrow[TH + U + j]);
      }
      wfz[j][ks] = fz; wfc[j][ks] = fc;
    }
  }
  const float bz0 = bias[U], bz1 = bias[U + 1];
  const float bc0 = 2.0f * bias[TH + U], bc1 = 2.0f * bias[TH + U + 1];

  int llen[4];
  #pragma unroll
  for (int i = 0; i < 4; i++) llen[i] = s_len[q * 4 + i];

  // h-write positions: row i of unit-pair (U,U+1) -> one aligned u32
  const int hqq = (r >> 1) & 3, hhalf = r >> 3, hem0 = (2 * r) & 3;
  int hwp[4];
  #pragma unroll
  for (int i = 0; i < 4; i++)
    hwp[i] = (((2 + w) * 4 + hqq) * 16 + ((q * 4 + i) ^ hqq)) * 8 + hhalf * 4 + hem0;

  float hreg[2][4];
  if (t0 == 0) {
    #pragma unroll
    for (int j = 0; j < 2; j++)
      #pragma unroll
      for (int i = 0; i < 4; i++) hreg[j][i] = 0.0f;
    for (int i = tid; i < 2048; i += 256) ldsA[0][1024 + i] = 0;
  } else {
    #pragma unroll
    for (int j = 0; j < 2; j++)
      #pragma unroll
      for (int i = 0; i < 4; i++)
        hreg[j][i] = wsH[(blk * TH + U + j) * 16 + q * 4 + i];
    #pragma unroll
    for (int i = 0; i < 4; i++)
      *(unsigned*)&ldsA[0][hwp[i]] = pk2bf(hreg[0][i], hreg[1][i]);
  }
  uint4* hhu4 = (uint4*)hh;
  const int hlane = q * 64 + w * 16 + r;   // uint4 idx within 256-uint4 slot
  __syncthreads();

#define SUB(T_, PAR, XR)                                                       \
  {                                                                            \
    const int t_ = (T_);                                                       \
    {  /* stage x(t_+1) into the write buffer; then reissue XR for t_+5 */     \
      uint2 pv; pv.x = pk2bf(XR[0], XR[1]); pv.y = pk2bf(XR[2], XR[3]);        \
      *(uint2*)&ldsA[(PAR) ^ 1][xpos] = pv;                                    \
    }                                                                          \
    XLD(t_ + 5, XR)                                                            \
    const ushort* Ab = ldsA[PAR];                                              \
    bf16x8 af0 = *(const bf16x8*)&Ab[((0 * 4 + q) * 16 + rxq) * 8];            \
    bf16x8 af1 = *(const bf16x8*)&Ab[((1 * 4 + q) * 16 + rxq) * 8];            \
    bf16x8 af2 = *(const bf16x8*)&Ab[((2 * 4 + q) * 16 + rxq) * 8];            \
    bf16x8 af3 = *(const bf16x8*)&Ab[((3 * 4 + q) * 16 + rxq) * 8];            \
    bf16x8 af4 = *(const bf16x8*)&Ab[((4 * 4 + q) * 16 + rxq) * 8];            \
    bf16x8 af5 = *(const bf16x8*)&Ab[((5 * 4 + q) * 16 + rxq) * 8];            \
    f32x4 az0 = {bz0, bz0, bz0, bz0}, az1 = {bz1, bz1, bz1, bz1};              \
    f32x4 ac0 = {bc0, bc0, bc0, bc0}, ac1 = {bc1, bc1, bc1, bc1};              \
    __builtin_amdgcn_s_setprio(1);                                             \
    az0 = MFMA(af0, wfz[0][0], az0, 0, 0, 0);                                  \
    az1 = MFMA(af0, wfz[1][0], az1, 0, 0, 0);                                  \
    ac0 = MFMA(af0, wfc[0][0], ac0, 0, 0, 0);                                  \
    ac1 = MFMA(af0, wfc[1][0], ac1, 0, 0, 0);                                  \
    az0 = MFMA(af1, wfz[0][1], az0, 0, 0, 0);                                  \
    az1 = MFMA(af1, wfz[1][1], az1, 0, 0, 0);                                  \
    ac0 = MFMA(af1, wfc[0][1], ac0, 0, 0, 0);                                  \
    ac1 = MFMA(af1, wfc[1][1], ac1, 0, 0, 0);                                  \
    az0 = MFMA(af2, wfz[0][2], az0, 0, 0, 0);                                  \
    az1 = MFMA(af2, wfz[1][2], az1, 0, 0, 0);                                  \
    ac0 = MFMA(af2, wfc[0][2], ac0, 0, 0, 0);                                  \
    ac1 = MFMA(af2, wfc[1][2], ac1, 0, 0, 0);                                  \
    az0 = MFMA(af3, wfz[0][3], az0, 0, 0, 0);                                  \
    az1 = MFMA(af3, wfz[1][3], az1, 0, 0, 0);                                  \
    ac0 = MFMA(af3, wfc[0][3], ac0, 0, 0, 0);                                  \
    ac1 = MFMA(af3, wfc[1][3], ac1, 0, 0, 0);                                  \
    az0 = MFMA(af4, wfz[0][4], az0, 0, 0, 0);                                  \
    az1 = MFMA(af4, wfz[1][4], az1, 0, 0, 0);                                  \
    ac0 = MFMA(af4, wfc[0][4], ac0, 0, 0, 0);                                  \
    ac1 = MFMA(af4, wfc[1][4], ac1, 0, 0, 0);                                  \
    az0 = MFMA(af5, wfz[0][5], az0, 0, 0, 0);                                  \
    az1 = MFMA(af5, wfz[1][5], az1, 0, 0, 0);                                  \
    ac0 = MFMA(af5, wfc[0][5], ac0, 0, 0, 0);                                  \
    ac1 = MFMA(af5, wfc[1][5], ac1, 0, 0, 0);                                  \
    __builtin_amdgcn_s_setprio(0);                                             \
    _Pragma("unroll")                                                          \
    for (int i = 0; i < 4; i++) {                                              \
      float zv = __builtin_amdgcn_rcpf(1.0f + __expf(-az0[i]));                \
      float hc = 1.0f - 2.0f * __builtin_amdgcn_rcpf(1.0f + __expf(ac0[i]));   \
      float h  = hc + zv * (hreg[0][i] - hc);                                  \
      hreg[0][i] = (t_ < llen[i]) ? h : hreg[0][i];                            \
      zv = __builtin_amdgcn_rcpf(1.0f + __expf(-az1[i]));                      \
      hc = 1.0f - 2.0f * __builtin_amdgcn_rcpf(1.0f + __expf(ac1[i]));         \
      h  = hc + zv * (hreg[1][i] - hc);                                        \
      hreg[1][i] = (t_ < llen[i]) ? h : hreg[1][i];                            \
    }                                                                          \
    {  /* coalesced h-history store (fire & forget) */                         \
      uint4 hv;                                                                \
      hv.x = pk2bf(hreg[0][0], hreg[0][1]);                                    \
      hv.y = pk2bf(hreg[0][2], hreg[0][3]);                                    \
      hv.z = pk2bf(hreg[1][0], hreg[1][1]);                                    \
      hv.w = pk2bf(hreg[1][2], hreg[1][3]);                                    \
      hhu4[((size_t)(t_ - t0) * NBLK + blk) * 256 + hlane] = hv;               \
    }                                                                          \
    ushort* Aw = ldsA[(PAR) ^ 1];                                              \
    *(unsigned*)&Aw[hwp[0]] = pk2bf(hreg[0][0], hreg[1][0]);                   \
    *(unsigned*)&Aw[hwp[1]] = pk2bf(hreg[0][1], hreg[1][1]);                   \
    *(unsigned*)&Aw[hwp[2]] = pk2bf(hreg[0][2], hreg[1][2]);                   \
    *(unsigned*)&Aw[hwp[3]] = pk2bf(hreg[0][3], hreg[1][3]);                   \
    asm volatile("s_waitcnt lgkmcnt(0)" ::: "memory");                         \
    __builtin_amdgcn_s_barrier();                                              \
    __builtin_amdgcn_sched_barrier(0);                                         \
  }

  for (int t = t0; t < t1; t += 4) {   // (t1-t0) is a multiple of 4
    SUB(t + 0, 0, xA)
    SUB(t + 1, 1, xB)
    SUB(t + 2, 0, xC)
    SUB(t + 3, 1, xD)
  }
#undef SUB
#undef XLD

  // checkpoint h for next chunk
  #pragma unroll
  for (int j = 0; j < 2; j++)
    #pragma unroll
    for (int i = 0; i < 4; i++)
      wsH[(blk * TH + U + j) * 16 + q * 4 + i] = hreg[j][i];
}

// ---------------- ypost: y = h @ Wo + bo, store + masked BN stats --------
// hh layout: slot (s,blk) = 2048 ushorts, element (row, u) at
// ((row>>2)*128 + u)*4 + (row&3).
__global__ __launch_bounds__(256) void ypost_kernel(
    const int* __restrict__ lengths, const float* __restrict__ Wo,
    const float* __restrict__ bo, const ushort* __restrict__ hh,
    float* __restrict__ out, float* __restrict__ wsStats, int t0, int t1)
{
  __shared__ __align__(16) ushort hst[4][2048];   // per-wave h staging
  __shared__ float yts[4][16 * 17 + 4];           // per-wave transpose tile
  __shared__ float sstat[2][1024];                // block stats [sum/sq][o*16+n]
  const int tid = threadIdx.x;
  const int w = tid >> 6, l = tid & 63, q = l >> 4, r = l & 15;
  const int blk = blockIdx.x, g = blockIdx.y;

  const int nT = r;
  const int n = blk * 16 + nT;
  const int okT = (n < TN);
  const int bT = okT ? (n / TDD) : 0;
  const int dT = okT ? (n - bT * TDD) : 0;
  const int lenT = okT ? lengths[bT] : -1;

  for (int i = tid; i < 2048; i += 256) ((float*)sstat)[i] = 0.0f;

  bf16x8 wo[4][4];
  float bo4[4];
  #pragma unroll
  for (int jt = 0; jt < 4; jt++) {
    #pragma unroll
    for (int ks = 0; ks < 4; ks++) {
      bf16x8 f;
      #pragma unroll
      for (int e = 0; e < 8; e++)
        f[e] = (short)f2bf(Wo[(ks * 32 + kmap(e, q)) * TO + jt * 16 + r]);
      wo[jt][ks] = f;
    }
    bo4[jt] = bo[jt * 16 + r];
  }
  float ysum[16], ysq[16];
  #pragma unroll
  for (int i = 0; i < 16; i++) { ysum[i] = 0.0f; ysq[i] = 0.0f; }
  __syncthreads();

  const int len = t1 - t0;
  const int half = (len + 1) >> 1;
  const int sbeg = g * half;
  const int send = (len < sbeg + half) ? len : sbeg + half;

  for (int s = sbeg + w; s < send; s += 4) {
    const ushort* hp = hh + (((size_t)s * NBLK + blk) << 11);
    ushort* hl = hst[w];
    #pragma unroll
    for (int e4 = 0; e4 < 4; e4++)
      *(bf16x8*)&hl[l * 32 + e4 * 8] = *(const bf16x8*)&hp[l * 32 + e4 * 8];
    bf16x8 af[4];
    #pragma unroll
    for (int ks = 0; ks < 4; ks++) {
      bf16x8 f;
      #pragma unroll
      for (int e = 0; e < 8; e++) {
        int u = ks * 32 + kmap(e, q);
        f[e] = (short)hl[(((r >> 2) * 128 + u) << 2) + (r & 3)];
      }
      af[ks] = f;
    }
    const int tabs = t0 + s;
    const bool val = (tabs < lenT);
    float* yt = yts[w];
    #pragma unroll
    for (int jt = 0; jt < 4; jt++) {
      f32x4 acc = {bo4[jt], bo4[jt], bo4[jt], bo4[jt]};
      acc = MFMA(af[0], wo[jt][0], acc, 0, 0, 0);
      acc = MFMA(af[1], wo[jt][1], acc, 0, 0, 0);
      acc = MFMA(af[2], wo[jt][2], acc, 0, 0, 0);
      acc = MFMA(af[3], wo[jt][3], acc, 0, 0, 0);
      #pragma unroll
      for (int i = 0; i < 4; i++) yt[r * 17 + q * 4 + i] = acc[i];
      #pragma unroll
      for (int j = 0; j < 4; j++) {
        float v = yt[((l >> 4) + 4 * j) * 17 + nT];
        int oj = jt * 16 + (l >> 4) + 4 * j;
        if (okT) out[((size_t)(bT * TO + oj)) * TTD + tabs * TDD + dT] = v;
        int ci = jt * 4 + j;
        ysum[ci] += val ? v : 0.0f;
        ysq[ci]  += val ? v * v : 0.0f;
      }
    }
  }
  #pragma unroll
  for (int ci = 0; ci < 16; ci++) {
    int o = (ci >> 2) * 16 + (l >> 4) + 4 * (ci & 3);
    int c = o * 16 + nT;
    atomicAdd(&sstat[0][c], ysum[ci]);
    atomicAdd(&sstat[1][c], ysq[ci]);
  }
  __syncthreads();
  for (int c = tid; c < 1024; c += 256) {
    int o = c >> 4, nn = c & 15;
    int n2 = blk * 16 + nn;
    if (n2 < TN) {
      int b2 = n2 / TDD, d2 = n2 - b2 * TDD;
      atomicAdd(&wsStats[o * TDD + d2], sstat[0][c]);
      atomicAdd(&wsStats[ODCH + o * TDD + d2], sstat[1][c]);
    }
  }
}

// ---------------- BN finalize: per-channel scale/shift ------------------
__global__ __launch_bounds__(256) void finalize_kernel(
    const int* __restrict__ lengths, const float* __restrict__ gamma,
    const float* __restrict__ beta, float* __restrict__ wsStats)
{
  int ch = blockIdx.x * 256 + threadIdx.x;
  if (ch >= ODCH) return;
  int c = 0;
  #pragma unroll
  for (int b = 0; b < TB; b++) c += lengths[b];
  float inv = 1.0f / (float)c;
  float mean = wsStats[ch] * inv;
  float var = wsStats[ODCH + ch] * inv - mean * mean;
  float sc = rsqrtf(var + 1e-5f) * gamma[ch];
  wsStats[2 * ODCH + ch] = sc;
  wsStats[3 * ODCH + ch] = beta[ch] - mean * sc;
}

// ---------------- normalize (float4, scale/shift table) ------------------
__global__ __launch_bounds__(256) void norm_kernel(
    const int* __restrict__ lengths, const float* __restrict__ ss,
    float* __restrict__ out)
{
  int i4 = blockIdx.x * 256 + threadIdx.x;   // TOTAL/4 exact
  int idx = i4 * 4;
  float vv[4];
  *(float4*)vv = ((const float4*)out)[i4];
  int dq = idx / TDD; int d = idx - dq * TDD;
  int tq = dq / TT;   int tt = dq - tq * TT;
  int o = tq & 63;    int b = tq >> 6;
  float res[4];
  #pragma unroll
  for (int k = 0; k < 4; k++) {
    int ch = o * TDD + d;
    float r_ = 0.0f;
    if (tt < lengths[b])
      r_ = vv[k] * ss[ch] + ss[ODCH + ch];
    res[k] = r_;
    d++;
    if (d == TDD) { d = 0; tt++; if (tt == TT) { tt = 0; o++; if (o == 64) { o = 0; b++; } } }
  }
  ((float4*)out)[i4] = *(float4*)res;
}

extern "C" void kernel_launch(void* const* d_in, const int* in_sizes, int n_in,
                              void* d_out, int out_size, void* d_ws, size_t ws_size,
                              hipStream_t stream)
{
  const float* x       = (const float*)d_in[0];
  const int*   lengths = (const int*)d_in[1];
  const float* Wx      = (const float*)d_in[2];
  const float* Wh      = (const float*)d_in[3];
  const float* bias    = (const float*)d_in[4];
  const float* Wo      = (const float*)d_in[5];
  const float* bo      = (const float*)d_in[6];
  const float* gamma   = (const float*)d_in[7];
  const float* beta    = (const float*)d_in[8];
  float* out = (float*)d_out;

  float* ws = (float*)d_ws;
  float* wsStats = ws;                              // 4*ODCH
  float* wsH = ws + 4 * ODCH;                       // NBLK*128*16
  ushort* hh = (ushort*)(wsH + NBLK * TH * 16);     // h history, bf16
  const size_t fixedB = (size_t)(4 * ODCH + NBLK * TH * 16) * 4;
  const size_t perT = (size_t)NBLK * 2048 * 2;      // 331776 B per timestep

  int tch = TT;                                     // TT = 300 (mult of 4)
  size_t avail = ws_size > fixedB ? ws_size - fixedB : 0;
  size_t maxT = avail / perT;
  if (maxT < (size_t)TT) {
    tch = ((int)maxT) & ~3;
    if (tch < 4) tch = 4;
  }

  hipMemsetAsync(wsStats, 0, 2 * ODCH * sizeof(float), stream);
  for (int T0 = 0; T0 < TT; T0 += tch) {
    int T1 = T0 + tch; if (T1 > TT) T1 = TT;
    hipLaunchKernelGGL(gru_kernel, dim3(NBLK), dim3(256), 0, stream,
                       x, lengths, Wx, Wh, bias, hh, wsH, T0, T1);
    hipLaunchKernelGGL(ypost_kernel, dim3(NBLK, 2), dim3(256), 0, stream,
                       lengths, Wo, bo, hh, out, wsStats, T0, T1);
  }
  hipLaunchKernelGGL(finalize_kernel, dim3((ODCH + 255) / 256), dim3(256), 0, stream,
                     lengths, gamma, beta, wsStats);
  hipLaunchKernelGGL(norm_kernel, dim3(TOTAL / 4 / 256), dim3(256), 0, stream,
                     lengths, wsStats + 2 * ODCH, out);
}

// Round 14
// 265.580 us; speedup vs baseline: 3.6889x; 1.4149x over previous
//
#include <hip/hip_runtime.h>

#define TB 8
#define TC 64
#define TT 300
#define TDD 161
#define TH 128
#define TO 64
#define TN (TB * TDD)          // 1288 sequences
#define TWOH 256
#define TILE 16
#define NBLK 81                // ceil(1288/16)
#define NKS 6                  // (C+H)/32
#define ODCH (TO * TDD)        // 10304 channels
#define TOTAL (TB * TO * TT * TDD)      // 24729600
#define AFRAG (NKS * 4 * 16 * 8)        // 3072 ushorts per ring slot
#define TTD (TT * TDD)

typedef __attribute__((ext_vector_type(8))) short bf16x8;
typedef __attribute__((ext_vector_type(4))) float f32x4;

#define MFMA __builtin_amdgcn_mfma_f32_16x16x32_bf16

__device__ __forceinline__ ushort f2bf(float f) {
  union { float f; unsigned u; } v; v.f = f;
  return (ushort)((v.u + 0x7fffu + ((v.u >> 16) & 1u)) >> 16);  // RNE
}
__device__ __forceinline__ unsigned pk2bf(float lo, float hi) {
  unsigned r;
  asm("v_cvt_pk_bf16_f32 %0, %1, %2" : "=v"(r) : "v"(lo), "v"(hi));
  return r;
}

// k-mapping inside a 16x16x32 fragment; identical convention everywhere so any
// permutation error cancels in the contraction (verified R1-R13).
__device__ __forceinline__ int kmap(int e, int q) {
  return ((e < 4) ? 0 : 16) + q * 4 + (e & 3);
}

// 8-wave fused kernel. Waves 0-3: recurrence (R13 structure, 32 units/wave,
// packed LDS writes). Waves 4-7: y = h@Wo + bo consumers, 4-step lag, reading
// the 8-deep LDS A-frag ring. 2 waves/SIMD -> y work + recurrence latency
// overlap on the CU scheduler; no hh global round-trip; no ypost kernel.
__global__ __launch_bounds__(512, 2) void gru_kernel(
    const float* __restrict__ x, const int* __restrict__ lengths,
    const float* __restrict__ Wx, const float* __restrict__ Wh,
    const float* __restrict__ bias, const float* __restrict__ Wo,
    const float* __restrict__ bo, float* __restrict__ out,
    float* __restrict__ wsStats)
{
  __shared__ __align__(16) ushort ring[8][AFRAG];   // [x_t | h_{t-1}] frags
  __shared__ float yts[4][16 * 17 + 4];             // per-y-wave transpose tile
  __shared__ int s_b[TILE], s_d[TILE], s_len[TILE], s_ok[TILE];

  const int tid = threadIdx.x;
  const int w = tid >> 6, l = tid & 63, q = l >> 4, r = l & 15;
  const int rxq = r ^ q;
  const int blk = blockIdx.x;

  if (tid < TILE) {
    int n = blk * TILE + tid;
    int ok = (n < TN) ? 1 : 0;
    int b = ok ? (n / TDD) : 0;
    int d = ok ? (n - b * TDD) : 0;
    s_b[tid] = b; s_d[tid] = d; s_ok[tid] = ok;
    s_len[tid] = ok ? lengths[b] : -1;
  }
  __syncthreads();
  // zero h-part of ring slot 0 (h_{-1} = 0), all threads
  for (int i = tid; i < AFRAG - 1024; i += 512) ring[0][1024 + i] = 0;

  // ---------------- role variables ----------------
  int xok = 0, xpos = 0;
  long xbase = 0;
  float xA[4], xB[4], xC[4], xD[4];
  bf16x8 wfz[2][NKS], wfc[2][NKS];
  float bz0 = 0, bz1 = 0, bc0 = 0, bc1 = 0;
  int llen[4], hwp[4];
  float hreg[2][4] = {{0, 0, 0, 0}, {0, 0, 0, 0}};
  bf16x8 wo4[4];
  float bo_v = 0;
  int nT = 0, dT = 0, lenT = -1, okT = 0;
  long ybaseT[4] = {0, 0, 0, 0};
  int ochT[4] = {0, 0, 0, 0};
  float ysumT[4] = {0, 0, 0, 0}, ysqT[4] = {0, 0, 0, 0};

#define XLD(T_, D_)                                                            \
  { int tt_ = (T_); tt_ = (tt_ < TT) ? tt_ : (TT - 1);                         \
    _Pragma("unroll")                                                          \
    for (int e = 0; e < 4; e++)                                                \
      D_[e] = xok ? x[xbase + (long)e * TTD + tt_ * TDD] : 0.0f; }

  if (w < 4) {
    // ---- x loader: slot nn = tid&15 (d-adjacent lanes), cq = tid>>4
    const int xnn = tid & 15, xcq = tid >> 4;
    xok = s_ok[xnn];
    xbase = (long)(s_b[xnn] * TC + xcq * 4) * TTD + s_d[xnn];
    xpos = (((xcq >> 3) * 4 + (xcq & 3)) * 16 + (xnn ^ (xcq & 3))) * 8
           + ((xcq >> 2) & 1) * 4;
    {  // stage x(0) into ring slot 0
      float cx[4]; XLD(0, cx)
      uint2 pv; pv.x = pk2bf(cx[0], cx[1]); pv.y = pk2bf(cx[2], cx[3]);
      *(uint2*)&ring[0][xpos] = pv;
    }
    XLD(1, xA) XLD(2, xB) XLD(3, xC) XLD(4, xD)

    // gate B-frags; c-gate pre-scaled by 2 (exact pow2)
    const int U = w * 32 + 2 * r;
    #pragma unroll
    for (int j = 0; j < 2; j++) {
      #pragma unroll
      for (int ks = 0; ks < NKS; ks++) {
        bf16x8 fz, fc;
        #pragma unroll
        for (int e = 0; e < 8; e++) {
          int kg = ks * 32 + kmap(e, q);
          const float* Wrow = (kg < TC) ? &Wx[kg * TWOH] : &Wh[(kg - TC) * TWOH];
          fz[e] = (short)f2bf(Wrow[U + j]);
          fc[e] = (short)f2bf(2.0f * Wrow[TH + U + j]);
        }
        wfz[j][ks] = fz; wfc[j][ks] = fc;
      }
    }
    bz0 = bias[U]; bz1 = bias[U + 1];
    bc0 = 2.0f * bias[TH + U]; bc1 = 2.0f * bias[TH + U + 1];
    #pragma unroll
    for (int i = 0; i < 4; i++) llen[i] = s_len[q * 4 + i];
    const int hqq = (r >> 1) & 3, hhalf = r >> 3, hem0 = (2 * r) & 3;
    #pragma unroll
    for (int i = 0; i < 4; i++)
      hwp[i] = (((2 + w) * 4 + hqq) * 16 + ((q * 4 + i) ^ hqq)) * 8
               + hhalf * 4 + hem0;
  } else {
    const int w4 = w - 4;
    #pragma unroll
    for (int ks = 0; ks < 4; ks++) {
      bf16x8 f;
      #pragma unroll
      for (int e = 0; e < 8; e++)
        f[e] = (short)f2bf(Wo[(ks * 32 + kmap(e, q)) * TO + w4 * 16 + r]);
      wo4[ks] = f;
    }
    bo_v = bo[w4 * 16 + r];
    nT = l & 15;
    dT = s_d[nT]; lenT = s_len[nT]; okT = s_ok[nT];
    #pragma unroll
    for (int j = 0; j < 4; j++) {
      int oj = w4 * 16 + (l >> 4) + 4 * j;
      ybaseT[j] = (long)(s_b[nT] * TO + oj) * TTD + dT;
      ochT[j] = oj * TDD + dT;
    }
  }
  __syncthreads();

// ---- y-consumer body: y_{tm} from h_{tm} in ring slot (tm+1)&7
#define YB(TM_)                                                                \
  {                                                                            \
    const int tm_ = (TM_);                                                     \
    const ushort* Ah = ring[(tm_ + 1) & 7];                                    \
    bf16x8 ah0 = *(const bf16x8*)&Ah[((2 * 4 + q) * 16 + rxq) * 8];            \
    bf16x8 ah1 = *(const bf16x8*)&Ah[((3 * 4 + q) * 16 + rxq) * 8];            \
    bf16x8 ah2 = *(const bf16x8*)&Ah[((4 * 4 + q) * 16 + rxq) * 8];            \
    bf16x8 ah3 = *(const bf16x8*)&Ah[((5 * 4 + q) * 16 + rxq) * 8];            \
    f32x4 ya = {bo_v, bo_v, bo_v, bo_v};                                       \
    ya = MFMA(ah0, wo4[0], ya, 0, 0, 0);                                       \
    ya = MFMA(ah1, wo4[1], ya, 0, 0, 0);                                       \
    ya = MFMA(ah2, wo4[2], ya, 0, 0, 0);                                       \
    ya = MFMA(ah3, wo4[3], ya, 0, 0, 0);                                       \
    float* yt = yts[w - 4];                                                    \
    _Pragma("unroll")                                                          \
    for (int i = 0; i < 4; i++) yt[r * 17 + q * 4 + i] = ya[i];                \
    _Pragma("unroll")                                                          \
    for (int j = 0; j < 4; j++) {                                              \
      float v = yt[((l >> 4) + 4 * j) * 17 + nT];                              \
      if (okT) out[ybaseT[j] + (long)tm_ * TDD] = v;                           \
      bool val = (tm_ < lenT);                                                 \
      ysumT[j] += val ? v : 0.0f;                                              \
      ysqT[j]  += val ? v * v : 0.0f;                                          \
    }                                                                          \
  }

#define SUB(T_, XR)                                                            \
  {                                                                            \
    const int t_ = (T_);                                                       \
    if (w < 4) {                                                               \
      ushort* Aw = ring[(t_ + 1) & 7];                                         \
      { uint2 pv; pv.x = pk2bf(XR[0], XR[1]); pv.y = pk2bf(XR[2], XR[3]);      \
        *(uint2*)&Aw[xpos] = pv; }                                             \
      XLD(t_ + 5, XR)                                                          \
      const ushort* Ab = ring[t_ & 7];                                         \
      bf16x8 af0 = *(const bf16x8*)&Ab[((0 * 4 + q) * 16 + rxq) * 8];          \
      bf16x8 af1 = *(const bf16x8*)&Ab[((1 * 4 + q) * 16 + rxq) * 8];          \
      bf16x8 af2 = *(const bf16x8*)&Ab[((2 * 4 + q) * 16 + rxq) * 8];          \
      bf16x8 af3 = *(const bf16x8*)&Ab[((3 * 4 + q) * 16 + rxq) * 8];          \
      bf16x8 af4 = *(const bf16x8*)&Ab[((4 * 4 + q) * 16 + rxq) * 8];          \
      bf16x8 af5 = *(const bf16x8*)&Ab[((5 * 4 + q) * 16 + rxq) * 8];          \
      f32x4 az0 = {bz0, bz0, bz0, bz0}, az1 = {bz1, bz1, bz1, bz1};            \
      f32x4 ac0 = {bc0, bc0, bc0, bc0}, ac1 = {bc1, bc1, bc1, bc1};            \
      __builtin_amdgcn_s_setprio(1);                                           \
      az0 = MFMA(af0, wfz[0][0], az0, 0, 0, 0);                                \
      az1 = MFMA(af0, wfz[1][0], az1, 0, 0, 0);                                \
      ac0 = MFMA(af0, wfc[0][0], ac0, 0, 0, 0);                                \
      ac1 = MFMA(af0, wfc[1][0], ac1, 0, 0, 0);                                \
      az0 = MFMA(af1, wfz[0][1], az0, 0, 0, 0);                                \
      az1 = MFMA(af1, wfz[1][1], az1, 0, 0, 0);                                \
      ac0 = MFMA(af1, wfc[0][1], ac0, 0, 0, 0);                                \
      ac1 = MFMA(af1, wfc[1][1], ac1, 0, 0, 0);                                \
      az0 = MFMA(af2, wfz[0][2], az0, 0, 0, 0);                                \
      az1 = MFMA(af2, wfz[1][2], az1, 0, 0, 0);                                \
      ac0 = MFMA(af2, wfc[0][2], ac0, 0, 0, 0);                                \
      ac1 = MFMA(af2, wfc[1][2], ac1, 0, 0, 0);                                \
      az0 = MFMA(af3, wfz[0][3], az0, 0, 0, 0);                                \
      az1 = MFMA(af3, wfz[1][3], az1, 0, 0, 0);                                \
      ac0 = MFMA(af3, wfc[0][3], ac0, 0, 0, 0);                                \
      ac1 = MFMA(af3, wfc[1][3], ac1, 0, 0, 0);                                \
      az0 = MFMA(af4, wfz[0][4], az0, 0, 0, 0);                                \
      az1 = MFMA(af4, wfz[1][4], az1, 0, 0, 0);                                \
      ac0 = MFMA(af4, wfc[0][4], ac0, 0, 0, 0);                                \
      ac1 = MFMA(af4, wfc[1][4], ac1, 0, 0, 0);                                \
      az0 = MFMA(af5, wfz[0][5], az0, 0, 0, 0);                                \
      az1 = MFMA(af5, wfz[1][5], az1, 0, 0, 0);                                \
      ac0 = MFMA(af5, wfc[0][5], ac0, 0, 0, 0);                                \
      ac1 = MFMA(af5, wfc[1][5], ac1, 0, 0, 0);                                \
      __builtin_amdgcn_s_setprio(0);                                           \
      _Pragma("unroll")                                                        \
      for (int i = 0; i < 4; i++) {                                            \
        float zv = __builtin_amdgcn_rcpf(1.0f + __expf(-az0[i]));              \
        float hc = 1.0f - 2.0f * __builtin_amdgcn_rcpf(1.0f + __expf(ac0[i])); \
        float h  = hc + zv * (hreg[0][i] - hc);                                \
        hreg[0][i] = (t_ < llen[i]) ? h : hreg[0][i];                          \
        zv = __builtin_amdgcn_rcpf(1.0f + __expf(-az1[i]));                    \
        hc = 1.0f - 2.0f * __builtin_amdgcn_rcpf(1.0f + __expf(ac1[i]));       \
        h  = hc + zv * (hreg[1][i] - hc);                                      \
        hreg[1][i] = (t_ < llen[i]) ? h : hreg[1][i];                          \
      }                                                                        \
      *(unsigned*)&Aw[hwp[0]] = pk2bf(hreg[0][0], hreg[1][0]);                 \
      *(unsigned*)&Aw[hwp[1]] = pk2bf(hreg[0][1], hreg[1][1]);                 \
      *(unsigned*)&Aw[hwp[2]] = pk2bf(hreg[0][2], hreg[1][2]);                 \
      *(unsigned*)&Aw[hwp[3]] = pk2bf(hreg[0][3], hreg[1][3]);                 \
    } else if (t_ >= 4) {                                                      \
      YB(t_ - 4)                                                               \
    }                                                                          \
    asm volatile("s_waitcnt lgkmcnt(0)" ::: "memory");                         \
    __builtin_amdgcn_s_barrier();                                              \
    __builtin_amdgcn_sched_barrier(0);                                         \
  }

  for (int t = 0; t < TT; t += 4) {   // TT = 300, multiple of 4
    SUB(t + 0, xA)
    SUB(t + 1, xB)
    SUB(t + 2, xC)
    SUB(t + 3, xD)
  }
#undef SUB
#undef XLD

  // epilogue: y_{TT-4..TT-1} (ring slots still live), then stats flush
  if (w >= 4) {
    YB(TT - 4) YB(TT - 3) YB(TT - 2) YB(TT - 1)
    #pragma unroll
    for (int j = 0; j < 4; j++) {
      if (okT) {
        atomicAdd(&wsStats[ochT[j]], ysumT[j]);
        atomicAdd(&wsStats[ODCH + ochT[j]], ysqT[j]);
      }
    }
  }
#undef YB
}

// ---------------- BN finalize: per-channel scale/shift ------------------
__global__ __launch_bounds__(256) void finalize_kernel(
    const int* __restrict__ lengths, const float* __restrict__ gamma,
    const float* __restrict__ beta, float* __restrict__ wsStats)
{
  int ch = blockIdx.x * 256 + threadIdx.x;
  if (ch >= ODCH) return;
  int c = 0;
  #pragma unroll
  for (int b = 0; b < TB; b++) c += lengths[b];
  float inv = 1.0f / (float)c;
  float mean = wsStats[ch] * inv;
  float var = wsStats[ODCH + ch] * inv - mean * mean;
  float sc = rsqrtf(var + 1e-5f) * gamma[ch];
  wsStats[2 * ODCH + ch] = sc;
  wsStats[3 * ODCH + ch] = beta[ch] - mean * sc;
}

// ---------------- normalize (float4, scale/shift table) ------------------
__global__ __launch_bounds__(256) void norm_kernel(
    const int* __restrict__ lengths, const float* __restrict__ ss,
    float* __restrict__ out)
{
  int i4 = blockIdx.x * 256 + threadIdx.x;   // TOTAL/4 exact
  int idx = i4 * 4;
  float vv[4];
  *(float4*)vv = ((const float4*)out)[i4];
  int dq = idx / TDD; int d = idx - dq * TDD;
  int tq = dq / TT;   int tt = dq - tq * TT;
  int o = tq & 63;    int b = tq >> 6;
  float res[4];
  #pragma unroll
  for (int k = 0; k < 4; k++) {
    int ch = o * TDD + d;
    float r_ = 0.0f;
    if (tt < lengths[b])
      r_ = vv[k] * ss[ch] + ss[ODCH + ch];
    res[k] = r_;
    d++;
    if (d == TDD) { d = 0; tt++; if (tt == TT) { tt = 0; o++; if (o == 64) { o = 0; b++; } } }
  }
  ((float4*)out)[i4] = *(float4*)res;
}

extern "C" void kernel_launch(void* const* d_in, const int* in_sizes, int n_in,
                              void* d_out, int out_size, void* d_ws, size_t ws_size,
                              hipStream_t stream)
{
  const float* x       = (const float*)d_in[0];
  const int*   lengths = (const int*)d_in[1];
  const float* Wx      = (const float*)d_in[2];
  const float* Wh      = (const float*)d_in[3];
  const float* bias    = (const float*)d_in[4];
  const float* Wo      = (const float*)d_in[5];
  const float* bo      = (const float*)d_in[6];
  const float* gamma   = (const float*)d_in[7];
  const float* beta    = (const float*)d_in[8];
  float* out = (float*)d_out;
  float* wsStats = (float*)d_ws;   // 4*ODCH floats

  hipMemsetAsync(wsStats, 0, 2 * ODCH * sizeof(float), stream);
  hipLaunchKernelGGL(gru_kernel, dim3(NBLK), dim3(512), 0, stream,
                     x, lengths, Wx, Wh, bias, Wo, bo, out, wsStats);
  hipLaunchKernelGGL(finalize_kernel, dim3((ODCH + 255) / 256), dim3(256), 0, stream,
                     lengths, gamma, beta, wsStats);
  hipLaunchKernelGGL(norm_kernel, dim3(TOTAL / 4 / 256), dim3(256), 0, stream,
                     lengths, wsStats + 2 * ODCH, out);
}

// Round 15
// 235.805 us; speedup vs baseline: 4.1547x; 1.1263x over previous
//
#include <hip/hip_runtime.h>

#define TB 8
#define TC 64
#define TT 300
#define TDD 161
#define TH 128
#define TO 64
#define TN (TB * TDD)          // 1288 sequences
#define TWOH 256
#define TILE 16
#define NBLK 81                // ceil(1288/16)
#define NKS 6                  // (C+H)/32
#define ODCH (TO * TDD)        // 10304 channels
#define TOTAL (TB * TO * TT * TDD)      // 24729600
#define AFRAG (NKS * 4 * 16 * 8)        // 3072 ushorts per ring slot
#define TTD (TT * TDD)

typedef __attribute__((ext_vector_type(8))) short bf16x8;
typedef __attribute__((ext_vector_type(4))) float f32x4;

#define MFMA __builtin_amdgcn_mfma_f32_16x16x32_bf16

__device__ __forceinline__ ushort f2bf(float f) {
  union { float f; unsigned u; } v; v.f = f;
  return (ushort)((v.u + 0x7fffu + ((v.u >> 16) & 1u)) >> 16);  // RNE
}
__device__ __forceinline__ unsigned pk2bf(float lo, float hi) {
  unsigned r;
  asm("v_cvt_pk_bf16_f32 %0, %1, %2" : "=v"(r) : "v"(lo), "v"(hi));
  return r;
}

// k-mapping inside a 16x16x32 fragment; identical convention everywhere so any
// permutation error cancels in the contraction (verified R1-R14).
__device__ __forceinline__ int kmap(int e, int q) {
  return ((e < 4) ? 0 : 16) + q * 4 + (e & 3);
}

// 8-wave fused kernel. Waves 0-3: recurrence ONLY (24 MFMA + gates + packed
// h-write; no x machinery -> shorter critical path + light lgkm drain).
// Waves 4-7: y-consumers (4-step lag via 8-deep ring) + the ENTIRE x pipeline
// (register-renamed depth-4 rotation + staging into the ring's x-region).
// x region (ushort idx < 1024) and h region (>= 1024) are disjoint; slot s is
// x-written at step s-1, read at s; all reads done by s+3; rewritten s+7.
__global__ __launch_bounds__(512, 2) void gru_kernel(
    const float* __restrict__ x, const int* __restrict__ lengths,
    const float* __restrict__ Wx, const float* __restrict__ Wh,
    const float* __restrict__ bias, const float* __restrict__ Wo,
    const float* __restrict__ bo, float* __restrict__ out,
    float* __restrict__ wsStats)
{
  __shared__ __align__(16) ushort ring[8][AFRAG];   // [x_t | h_{t-1}] frags
  __shared__ float yts[4][16 * 17 + 4];             // per-y-wave transpose tile
  __shared__ int s_b[TILE], s_d[TILE], s_len[TILE], s_ok[TILE];

  const int tid = threadIdx.x;
  const int w = tid >> 6, l = tid & 63, q = l >> 4, r = l & 15;
  const int rxq = r ^ q;
  const int blk = blockIdx.x;

  if (tid < TILE) {
    int n = blk * TILE + tid;
    int ok = (n < TN) ? 1 : 0;
    int b = ok ? (n / TDD) : 0;
    int d = ok ? (n - b * TDD) : 0;
    s_b[tid] = b; s_d[tid] = d; s_ok[tid] = ok;
    s_len[tid] = ok ? lengths[b] : -1;
  }
  __syncthreads();
  // zero h-part of ring slot 0 (h_{-1} = 0), all threads
  for (int i = tid; i < AFRAG - 1024; i += 512) ring[0][1024 + i] = 0;

  // ---------------- role variables ----------------
  int xok = 0, xpos = 0;
  long xbase = 0;
  float xA[4], xB[4], xC[4], xD[4];
  bf16x8 wfz[2][NKS], wfc[2][NKS];
  float bz0 = 0, bz1 = 0, bc0 = 0, bc1 = 0;
  int llen[4], hwp[4];
  float hreg[2][4] = {{0, 0, 0, 0}, {0, 0, 0, 0}};
  bf16x8 wo4[4];
  float bo_v = 0;
  int nT = 0, dT = 0, lenT = -1, okT = 0;
  long ybaseT[4] = {0, 0, 0, 0};
  int ochT[4] = {0, 0, 0, 0};
  float ysumT[4] = {0, 0, 0, 0}, ysqT[4] = {0, 0, 0, 0};

#define XLD(T_, D_)                                                            \
  { int tt_ = (T_); tt_ = (tt_ < TT) ? tt_ : (TT - 1);                         \
    _Pragma("unroll")                                                          \
    for (int e = 0; e < 4; e++)                                                \
      D_[e] = xok ? x[xbase + (long)e * TTD + tt_ * TDD] : 0.0f; }

  if (w < 4) {
    // ---- recurrence wave setup: gate B-frags; c pre-scaled by 2 (exact)
    const int U = w * 32 + 2 * r;
    #pragma unroll
    for (int j = 0; j < 2; j++) {
      #pragma unroll
      for (int ks = 0; ks < NKS; ks++) {
        bf16x8 fz, fc;
        #pragma unroll
        for (int e = 0; e < 8; e++) {
          int kg = ks * 32 + kmap(e, q);
          const float* Wrow = (kg < TC) ? &Wx[kg * TWOH] : &Wh[(kg - TC) * TWOH];
          fz[e] = (short)f2bf(Wrow[U + j]);
          fc[e] = (short)f2bf(2.0f * Wrow[TH + U + j]);
        }
        wfz[j][ks] = fz; wfc[j][ks] = fc;
      }
    }
    bz0 = bias[U]; bz1 = bias[U + 1];
    bc0 = 2.0f * bias[TH + U]; bc1 = 2.0f * bias[TH + U + 1];
    #pragma unroll
    for (int i = 0; i < 4; i++) llen[i] = s_len[q * 4 + i];
    const int hqq = (r >> 1) & 3, hhalf = r >> 3, hem0 = (2 * r) & 3;
    #pragma unroll
    for (int i = 0; i < 4; i++)
      hwp[i] = (((2 + w) * 4 + hqq) * 16 + ((q * 4 + i) ^ hqq)) * 8
               + hhalf * 4 + hem0;
  } else {
    // ---- y-wave setup: Wo frags + transposed-store info
    const int w4 = w - 4;
    #pragma unroll
    for (int ks = 0; ks < 4; ks++) {
      bf16x8 f;
      #pragma unroll
      for (int e = 0; e < 8; e++)
        f[e] = (short)f2bf(Wo[(ks * 32 + kmap(e, q)) * TO + w4 * 16 + r]);
      wo4[ks] = f;
    }
    bo_v = bo[w4 * 16 + r];
    nT = l & 15;
    dT = s_d[nT]; lenT = s_len[nT]; okT = s_ok[nT];
    #pragma unroll
    for (int j = 0; j < 4; j++) {
      int oj = w4 * 16 + (l >> 4) + 4 * j;
      ybaseT[j] = (long)(s_b[nT] * TO + oj) * TTD + dT;
      ochT[j] = oj * TDD + dT;
    }
    // ---- x pipeline (256 y-threads): slot nn = tid2&15, cq = tid2>>4
    const int tid2 = tid - 256;
    const int xnn = tid2 & 15, xcq = tid2 >> 4;
    xok = s_ok[xnn];
    xbase = (long)(s_b[xnn] * TC + xcq * 4) * TTD + s_d[xnn];
    xpos = (((xcq >> 3) * 4 + (xcq & 3)) * 16 + (xnn ^ (xcq & 3))) * 8
           + ((xcq >> 2) & 1) * 4;
    {  // stage x(0) into ring slot 0
      float cx[4]; XLD(0, cx)
      uint2 pv; pv.x = pk2bf(cx[0], cx[1]); pv.y = pk2bf(cx[2], cx[3]);
      *(uint2*)&ring[0][xpos] = pv;
    }
    XLD(1, xA) XLD(2, xB) XLD(3, xC) XLD(4, xD)
  }
  __syncthreads();

// ---- y-consumer body: y_{tm} from h_{tm} in ring slot (tm+1)&7
#define YB(TM_)                                                                \
  {                                                                            \
    const int tm_ = (TM_);                                                     \
    const ushort* Ah = ring[(tm_ + 1) & 7];                                    \
    bf16x8 ah0 = *(const bf16x8*)&Ah[((2 * 4 + q) * 16 + rxq) * 8];            \
    bf16x8 ah1 = *(const bf16x8*)&Ah[((3 * 4 + q) * 16 + rxq) * 8];            \
    bf16x8 ah2 = *(const bf16x8*)&Ah[((4 * 4 + q) * 16 + rxq) * 8];            \
    bf16x8 ah3 = *(const bf16x8*)&Ah[((5 * 4 + q) * 16 + rxq) * 8];            \
    f32x4 ya = {bo_v, bo_v, bo_v, bo_v};                                       \
    ya = MFMA(ah0, wo4[0], ya, 0, 0, 0);                                       \
    ya = MFMA(ah1, wo4[1], ya, 0, 0, 0);                                       \
    ya = MFMA(ah2, wo4[2], ya, 0, 0, 0);                                       \
    ya = MFMA(ah3, wo4[3], ya, 0, 0, 0);                                       \
    float* yt = yts[w - 4];                                                    \
    _Pragma("unroll")                                                          \
    for (int i = 0; i < 4; i++) yt[r * 17 + q * 4 + i] = ya[i];                \
    _Pragma("unroll")                                                          \
    for (int j = 0; j < 4; j++) {                                              \
      float v = yt[((l >> 4) + 4 * j) * 17 + nT];                              \
      if (okT) out[ybaseT[j] + (long)tm_ * TDD] = v;                           \
      bool val = (tm_ < lenT);                                                 \
      ysumT[j] += val ? v : 0.0f;                                              \
      ysqT[j]  += val ? v * v : 0.0f;                                          \
    }                                                                          \
  }

#define SUB(T_, XR)                                                            \
  {                                                                            \
    const int t_ = (T_);                                                       \
    if (w < 4) {                                                               \
      const ushort* Ab = ring[t_ & 7];                                         \
      bf16x8 af0 = *(const bf16x8*)&Ab[((0 * 4 + q) * 16 + rxq) * 8];          \
      bf16x8 af1 = *(const bf16x8*)&Ab[((1 * 4 + q) * 16 + rxq) * 8];          \
      bf16x8 af2 = *(const bf16x8*)&Ab[((2 * 4 + q) * 16 + rxq) * 8];          \
      bf16x8 af3 = *(const bf16x8*)&Ab[((3 * 4 + q) * 16 + rxq) * 8];          \
      bf16x8 af4 = *(const bf16x8*)&Ab[((4 * 4 + q) * 16 + rxq) * 8];          \
      bf16x8 af5 = *(const bf16x8*)&Ab[((5 * 4 + q) * 16 + rxq) * 8];          \
      f32x4 az0 = {bz0, bz0, bz0, bz0}, az1 = {bz1, bz1, bz1, bz1};            \
      f32x4 ac0 = {bc0, bc0, bc0, bc0}, ac1 = {bc1, bc1, bc1, bc1};            \
      __builtin_amdgcn_s_setprio(1);                                           \
      az0 = MFMA(af0, wfz[0][0], az0, 0, 0, 0);                                \
      az1 = MFMA(af0, wfz[1][0], az1, 0, 0, 0);                                \
      ac0 = MFMA(af0, wfc[0][0], ac0, 0, 0, 0);                                \
      ac1 = MFMA(af0, wfc[1][0], ac1, 0, 0, 0);                                \
      az0 = MFMA(af1, wfz[0][1], az0, 0, 0, 0);                                \
      az1 = MFMA(af1, wfz[1][1], az1, 0, 0, 0);                                \
      ac0 = MFMA(af1, wfc[0][1], ac0, 0, 0, 0);                                \
      ac1 = MFMA(af1, wfc[1][1], ac1, 0, 0, 0);                                \
      az0 = MFMA(af2, wfz[0][2], az0, 0, 0, 0);                                \
      az1 = MFMA(af2, wfz[1][2], az1, 0, 0, 0);                                \
      ac0 = MFMA(af2, wfc[0][2], ac0, 0, 0, 0);                                \
      ac1 = MFMA(af2, wfc[1][2], ac1, 0, 0, 0);                                \
      az0 = MFMA(af3, wfz[0][3], az0, 0, 0, 0);                                \
      az1 = MFMA(af3, wfz[1][3], az1, 0, 0, 0);                                \
      ac0 = MFMA(af3, wfc[0][3], ac0, 0, 0, 0);                                \
      ac1 = MFMA(af3, wfc[1][3], ac1, 0, 0, 0);                                \
      az0 = MFMA(af4, wfz[0][4], az0, 0, 0, 0);                                \
      az1 = MFMA(af4, wfz[1][4], az1, 0, 0, 0);                                \
      ac0 = MFMA(af4, wfc[0][4], ac0, 0, 0, 0);                                \
      ac1 = MFMA(af4, wfc[1][4], ac1, 0, 0, 0);                                \
      az0 = MFMA(af5, wfz[0][5], az0, 0, 0, 0);                                \
      az1 = MFMA(af5, wfz[1][5], az1, 0, 0, 0);                                \
      ac0 = MFMA(af5, wfc[0][5], ac0, 0, 0, 0);                                \
      ac1 = MFMA(af5, wfc[1][5], ac1, 0, 0, 0);                                \
      __builtin_amdgcn_s_setprio(0);                                           \
      _Pragma("unroll")                                                        \
      for (int i = 0; i < 4; i++) {                                            \
        float zv = __builtin_amdgcn_rcpf(1.0f + __expf(-az0[i]));              \
        float hc = 1.0f - 2.0f * __builtin_amdgcn_rcpf(1.0f + __expf(ac0[i])); \
        float h  = hc + zv * (hreg[0][i] - hc);                                \
        hreg[0][i] = (t_ < llen[i]) ? h : hreg[0][i];                          \
        zv = __builtin_amdgcn_rcpf(1.0f + __expf(-az1[i]));                    \
        hc = 1.0f - 2.0f * __builtin_amdgcn_rcpf(1.0f + __expf(ac1[i]));       \
        h  = hc + zv * (hreg[1][i] - hc);                                      \
        hreg[1][i] = (t_ < llen[i]) ? h : hreg[1][i];                          \
      }                                                                        \
      ushort* Aw = ring[(t_ + 1) & 7];                                         \
      *(unsigned*)&Aw[hwp[0]] = pk2bf(hreg[0][0], hreg[1][0]);                 \
      *(unsigned*)&Aw[hwp[1]] = pk2bf(hreg[0][1], hreg[1][1]);                 \
      *(unsigned*)&Aw[hwp[2]] = pk2bf(hreg[0][2], hreg[1][2]);                 \
      *(unsigned*)&Aw[hwp[3]] = pk2bf(hreg[0][3], hreg[1][3]);                 \
    } else {                                                                   \
      {  /* stage x(t_+1) into ring[(t_+1)&7]; reissue XR for t_+5 */          \
        uint2 pv; pv.x = pk2bf(XR[0], XR[1]); pv.y = pk2bf(XR[2], XR[3]);      \
        *(uint2*)&ring[(t_ + 1) & 7][xpos] = pv;                               \
      }                                                                        \
      XLD(t_ + 5, XR)                                                          \
      if (t_ >= 4) { YB(t_ - 4) }                                              \
    }                                                                          \
    asm volatile("s_waitcnt lgkmcnt(0)" ::: "memory");                         \
    __builtin_amdgcn_s_barrier();                                              \
    __builtin_amdgcn_sched_barrier(0);                                         \
  }

  for (int t = 0; t < TT; t += 4) {   // TT = 300, multiple of 4
    SUB(t + 0, xA)
    SUB(t + 1, xB)
    SUB(t + 2, xC)
    SUB(t + 3, xD)
  }
#undef SUB
#undef XLD

  // epilogue: y_{TT-4..TT-1} (ring slots still live), then stats flush
  if (w >= 4) {
    YB(TT - 4) YB(TT - 3) YB(TT - 2) YB(TT - 1)
    #pragma unroll
    for (int j = 0; j < 4; j++) {
      if (okT) {
        atomicAdd(&wsStats[ochT[j]], ysumT[j]);
        atomicAdd(&wsStats[ODCH + ochT[j]], ysqT[j]);
      }
    }
  }
#undef YB
}

// ---------------- BN finalize: per-channel scale/shift ------------------
__global__ __launch_bounds__(256) void finalize_kernel(
    const int* __restrict__ lengths, const float* __restrict__ gamma,
    const float* __restrict__ beta, float* __restrict__ wsStats)
{
  int ch = blockIdx.x * 256 + threadIdx.x;
  if (ch >= ODCH) return;
  int c = 0;
  #pragma unroll
  for (int b = 0; b < TB; b++) c += lengths[b];
  float inv = 1.0f / (float)c;
  float mean = wsStats[ch] * inv;
  float var = wsStats[ODCH + ch] * inv - mean * mean;
  float sc = rsqrtf(var + 1e-5f) * gamma[ch];
  wsStats[2 * ODCH + ch] = sc;
  wsStats[3 * ODCH + ch] = beta[ch] - mean * sc;
}

// ---------------- normalize (float4, scale/shift table) ------------------
__global__ __launch_bounds__(256) void norm_kernel(
    const int* __restrict__ lengths, const float* __restrict__ ss,
    float* __restrict__ out)
{
  int i4 = blockIdx.x * 256 + threadIdx.x;   // TOTAL/4 exact
  int idx = i4 * 4;
  float vv[4];
  *(float4*)vv = ((const float4*)out)[i4];
  int dq = idx / TDD; int d = idx - dq * TDD;
  int tq = dq / TT;   int tt = dq - tq * TT;
  int o = tq & 63;    int b = tq >> 6;
  float res[4];
  #pragma unroll
  for (int k = 0; k < 4; k++) {
    int ch = o * TDD + d;
    float r_ = 0.0f;
    if (tt < lengths[b])
      r_ = vv[k] * ss[ch] + ss[ODCH + ch];
    res[k] = r_;
    d++;
    if (d == TDD) { d = 0; tt++; if (tt == TT) { tt = 0; o++; if (o == 64) { o = 0; b++; } } }
  }
  ((float4*)out)[i4] = *(float4*)res;
}

extern "C" void kernel_launch(void* const* d_in, const int* in_sizes, int n_in,
                              void* d_out, int out_size, void* d_ws, size_t ws_size,
                              hipStream_t stream)
{
  const float* x       = (const float*)d_in[0];
  const int*   lengths = (const int*)d_in[1];
  const float* Wx      = (const float*)d_in[2];
  const float* Wh      = (const float*)d_in[3];
  const float* bias    = (const float*)d_in[4];
  const float* Wo      = (const float*)d_in[5];
  const float* bo      = (const float*)d_in[6];
  const float* gamma   = (const float*)d_in[7];
  const float* beta    = (const float*)d_in[8];
  float* out = (float*)d_out;
  float* wsStats = (float*)d_ws;   // 4*ODCH floats

  hipMemsetAsync(wsStats, 0, 2 * ODCH * sizeof(float), stream);
  hipLaunchKernelGGL(gru_kernel, dim3(NBLK), dim3(512), 0, stream,
                     x, lengths, Wx, Wh, bias, Wo, bo, out, wsStats);
  hipLaunchKernelGGL(finalize_kernel, dim3((ODCH + 255) / 256), dim3(256), 0, stream,
                     lengths, gamma, beta, wsStats);
  hipLaunchKernelGGL(norm_kernel, dim3(TOTAL / 4 / 256), dim3(256), 0, stream,
                     lengths, wsStats + 2 * ODCH, out);
}